// Round 9
// baseline (1606.634 us; speedup 1.0000x reference)
//
#include <hip/hip_runtime.h>
#include <hip/hip_bf16.h>

#define D_MODEL 256
#define D_STATE 64
#define MCON    64
#define TLEN    1024
#define BATCH   4
#define NEG_INF -1e9f
#define CSTRIDE 68

// ---------------- DPP wave-64 helpers ----------------
template <int CTRL, int RM>
__device__ __forceinline__ float dpp_f(float x) {
    int xi = __float_as_int(x);
    int r  = __builtin_amdgcn_update_dpp(xi, xi, CTRL, RM, 0xf, false);
    return __int_as_float(r);
}
template <int CTRL, int RM>
__device__ __forceinline__ int dpp_i(int x) {
    return __builtin_amdgcn_update_dpp(x, x, CTRL, RM, 0xf, false);
}
__device__ __forceinline__ float bcast_lane(float x, int lane) {
    return __int_as_float(__builtin_amdgcn_readlane(__float_as_int(x), lane));
}
__device__ __forceinline__ float wave_sum(float x) {
    x += dpp_f<0x111, 0xf>(x);
    x += dpp_f<0x112, 0xf>(x);
    x += dpp_f<0x114, 0xf>(x);
    x += dpp_f<0x118, 0xf>(x);
    x += dpp_f<0x142, 0xa>(x);
    x += dpp_f<0x143, 0xc>(x);
    return bcast_lane(x, 63);
}
__device__ __forceinline__ float wave_max(float x) {
    x = fmaxf(x, dpp_f<0x111, 0xf>(x));
    x = fmaxf(x, dpp_f<0x112, 0xf>(x));
    x = fmaxf(x, dpp_f<0x114, 0xf>(x));
    x = fmaxf(x, dpp_f<0x118, 0xf>(x));
    x = fmaxf(x, dpp_f<0x142, 0xa>(x));
    x = fmaxf(x, dpp_f<0x143, 0xc>(x));
    return bcast_lane(x, 63);
}
template <int CTRL, int RM>
__device__ __forceinline__ void maxarg_stage(float& v, int& i) {
    float ov = dpp_f<CTRL, RM>(v);
    int   oi = dpp_i<CTRL, RM>(i);
    const bool better = (ov > v) || (ov == v && oi < i);
    v = better ? ov : v;
    i = better ? oi : i;
}
// argmax over scores with first-index tiebreak (R2-validated semantics)
__device__ __forceinline__ int wave_argmax(float v, int lane) {
    int i = lane;
    maxarg_stage<0x111, 0xf>(v, i);
    maxarg_stage<0x112, 0xf>(v, i);
    maxarg_stage<0x114, 0xf>(v, i);
    maxarg_stage<0x118, 0xf>(v, i);
    maxarg_stage<0x142, 0xa>(v, i);
    maxarg_stage<0x143, 0xc>(v, i);
    return __builtin_amdgcn_readlane(i, 63);
}

// ---------------------------------------------------------------------------
// Kernel 1: per-token projections (unchanged — passed R2..R8).
// ---------------------------------------------------------------------------
__global__ __launch_bounds__(256) void proj_kernel(
    const float* __restrict__ x,
    const float* __restrict__ Wq, const float* __restrict__ bq,
    const float* __restrict__ Wk, const float* __restrict__ bk,
    const float* __restrict__ Wv, const float* __restrict__ bv,
    float* __restrict__ q_ws, float* __restrict__ k_ws, float* __restrict__ v_ws)
{
    const int token = blockIdx.x;
    const int tid = threadIdx.x;
    __shared__ float sx[D_MODEL];
    sx[tid] = x[token * D_MODEL + tid];
    __syncthreads();

    float acc = 0.f;
    #pragma unroll 8
    for (int i = 0; i < D_MODEL; ++i)
        acc += sx[i] * Wv[i * D_MODEL + tid];
    acc += bv[tid];
    v_ws[token * D_MODEL + tid] = acc;

    if (tid < 128) {
        const int j = tid & 63;
        const float* W  = (tid < 64) ? Wq : Wk;
        const float* bb = (tid < 64) ? bq : bk;
        float a = 0.f;
        #pragma unroll 8
        for (int i = 0; i < D_MODEL; ++i)
            a += sx[i] * W[i * D_STATE + j];
        a += bb[j];
        float s2 = a * a;
        #pragma unroll
        for (int off = 1; off < 64; off <<= 1) s2 += __shfl_xor(s2, off, 64);
        float nrm = fmaxf(sqrtf(s2), 1e-12f);
        float o = a / nrm;
        if (tid < 64) q_ws[token * D_STATE + j] = o;
        else          k_ws[token * D_STATE + j] = o;
    }
}

// ---------------------------------------------------------------------------
// Kernel 2: CONTROL scan — SINGLE 64-lane wave per sequence. Zero barriers.
// C row-view in registers (lane l = row l, 64 VGPRs) for sims; C across-lane
// in LDS for the EMA update; changed row transposed back through LDS
// (same-wave DS ordering => no sync needed). V in LDS (single wave).
// All reduction trees bit-identical to R8 (passed, absmax 9.77e-4).
// ---------------------------------------------------------------------------
__global__ __launch_bounds__(64) void scan_kernel(
    const float* __restrict__ q_ws, const float* __restrict__ k_ws,
    const float* __restrict__ v_ws,
    float* __restrict__ sims_ws, int* __restrict__ n_ws,
    int* __restrict__ ver_ws, float* __restrict__ vlog_ws,
    const float* __restrict__ ls_p)
{
    const int b = blockIdx.x;
    const int l = threadIdx.x;          // lane 0..63
    const float scale = fminf(expf(ls_p[0]), 100.f);

    __shared__ __align__(16) float sCT[MCON * CSTRIDE];  // across-lane C (17.4 KB)
    __shared__ __align__(16) float sV[MCON * D_MODEL];   // 64 KB

    const float4 zero4 = make_float4(0.f, 0.f, 0.f, 0.f);
    for (int i = l; i < MCON * CSTRIDE; i += 64) sCT[i] = 0.f;
    #pragma unroll
    for (int i = 0; i < 64; ++i) ((float4*)sV)[i * 64 + l] = zero4;

    float C[64];                        // row l of centroids, per lane
    #pragma unroll
    for (int j = 0; j < 64; ++j) C[j] = 0.f;

    float cnt_l = 0.f;                  // counts[l] in lane l
    int   ver_l = 0;                    // version pointer for concept l
    int   n     = 0;                    // uniform across lanes

    const float* qg = q_ws + b * TLEN * D_STATE;
    const float* kg = k_ws + b * TLEN * D_STATE;
    const float* vg = v_ws + b * TLEN * D_MODEL;
    float* vlog_b   = vlog_ws + (size_t)b * (TLEN + 1) * D_MODEL;

    // vlog slot 0 = zeros (targets of never-written version pointers)
    *(float4*)&vlog_b[4 * l] = zero4;

    // prefetch t = 0
    float  qv = qg[l];
    float  kv = kg[l];
    float4 vv = *(const float4*)&vg[4 * l];

    for (int t = 0; t < TLEN; ++t) {
        const int token = b * TLEN + t;
        const float  kk = kv;
        const float4 vt = vv;

        // prefetch t+1 (full-step slack)
        const int tn = (t + 1 < TLEN) ? t + 1 : t;
        const float  qn = qg[tn * D_STATE + l];
        const float  kn = kg[tn * D_STATE + l];
        const float4 vn = *(const float4*)&vg[tn * D_MODEL + 4 * l];

        // ---- sims: lane l computes C[l].q entirely in registers.
        // Same 4-chain serial part-tree as R8: p_part over j=16p..16p+15
        // in increasing order, combined (p0+p1)+(p2+p3). Bit-identical.
        float p0 = 0.f, p1 = 0.f, p2 = 0.f, p3 = 0.f;
        #pragma unroll
        for (int j = 0; j < 16; ++j) p0 += C[j]      * bcast_lane(qv, j);
        #pragma unroll
        for (int j = 0; j < 16; ++j) p1 += C[16 + j] * bcast_lane(qv, 16 + j);
        #pragma unroll
        for (int j = 0; j < 16; ++j) p2 += C[32 + j] * bcast_lane(qv, 32 + j);
        #pragma unroll
        for (int j = 0; j < 16; ++j) p3 += C[48 + j] * bcast_lane(qv, 48 + j);
        const float sim = (p0 + p1) + (p2 + p3);

        // ---- argmax over masked scores (R8 semantics) ----
        const float lg = ((l < n) ? sim : NEG_INF) * scale;
        const int   sel    = wave_argmax(lg, l);
        const float selSim = bcast_lane(sim,   sel);
        const float cnt    = bcast_lane(cnt_l, sel);

        // ---- LDS reads: across-lane C row sel + V row sel (issue early) ----
        const float  c_old = sCT[sel * CSTRIDE + l];
        const float4 vs    = *(const float4*)&sV[sel * D_MODEL + 4 * l];

        // ---- residual (tree == R8) ----
        float r = (vs.x - vt.x) * (vs.x - vt.x)
                + (vs.y - vt.y) * (vs.y - vt.y)
                + (vs.z - vt.z) * (vs.z - vt.z)
                + (vs.w - vt.w) * (vs.w - vt.w);
        const float residual = sqrtf(wave_sum(r) * (1.f / 256.f));

        // ---- flags (uniform) ----
        const bool has       = n > 0;
        const bool refine    = has && (n < MCON) &&
                               (selSim < 0.75f || residual > 1.0f);
        const bool do_add    = ((!has) || refine) && (n < MCON);
        const bool do_update = has && !refine;
        const int  chg       = do_update ? sel : n;   // exactly one change/step

        // ---- logs (pre-update views) ----
        sims_ws[(size_t)token * MCON + l] = sim;
        ver_ws[(size_t)token * MCON + l]  = ver_l;
        if (l == 0) n_ws[token] = n;

        // ---- V update + vlog ----
        float4 nv;
        nv.x = (vs.x * cnt + vt.x) / (cnt + 1.f);
        nv.y = (vs.y * cnt + vt.y) / (cnt + 1.f);
        nv.z = (vs.z * cnt + vt.z) / (cnt + 1.f);
        nv.w = (vs.w * cnt + vt.w) / (cnt + 1.f);
        float4 valV;
        valV.x = do_update ? nv.x : vt.x;
        valV.y = do_update ? nv.y : vt.y;
        valV.z = do_update ? nv.z : vt.z;
        valV.w = do_update ? nv.w : vt.w;
        *(float4*)&sV[chg * D_MODEL + 4 * l] = valV;
        *(float4*)&vlog_b[(size_t)(t + 1) * D_MODEL + 4 * l] = valV;

        // ---- C update in across-lane view (trees == R8) ----
        const float tmp   = 0.9f * c_old + 0.1f * kk;
        const float s2    = wave_sum(tmp * tmp);
        const float updc  = tmp / fmaxf(sqrtf(s2), 1e-12f);
        const float newC  = do_update ? updc : kk;
        sCT[chg * CSTRIDE + l] = newC;

        // ---- transpose changed row back into lane chg's registers.
        // Same-wave LDS ops process in order: reads below see the write above.
        if (l == chg) {
            #pragma unroll
            for (int jj = 0; jj < 16; ++jj) {
                const float4 cc = *(const float4*)&sCT[chg * CSTRIDE + 4 * jj];
                C[4 * jj + 0] = cc.x; C[4 * jj + 1] = cc.y;
                C[4 * jj + 2] = cc.z; C[4 * jj + 3] = cc.w;
            }
        }

        // ---- counts / versions / n ----
        if (l == sel && do_update) cnt_l = cnt + 1.f;
        if (l == n   && do_add)    cnt_l = 1.f;
        if (l == chg) ver_l = t + 1;
        n += do_add ? 1 : 0;

        qv = qn; kv = kn; vv = vn;
    }
}

// ---------------------------------------------------------------------------
// Kernel 3: PAYLOAD — parallel over tokens (unchanged — passed R8).
// ---------------------------------------------------------------------------
__global__ __launch_bounds__(256) void z_kernel(
    const float* __restrict__ sims_ws, const int* __restrict__ n_ws,
    const int* __restrict__ ver_ws, const float* __restrict__ vlog_ws,
    float* __restrict__ y_ws, const float* __restrict__ ls_p)
{
    const int token = blockIdx.x;
    const int b     = token >> 10;           // TLEN = 1024
    const int tid   = threadIdx.x;
    const int l     = tid & 63;
    const int wv    = tid >> 6;
    const float scale = fminf(expf(ls_p[0]), 100.f);

    __shared__ float sWt[MCON];
    __shared__ int   sVer[MCON];
    __shared__ int   sNtok;

    if (tid == 0) sNtok = n_ws[token];
    if (wv == 1) sVer[l] = ver_ws[(size_t)token * MCON + l];
    if (wv == 0) {
        const float simv = sims_ws[(size_t)token * MCON + l];
        const int nt = n_ws[token];
        const float lg = ((l < nt) ? simv : NEG_INF) * scale;
        const float mx = wave_max(lg);
        const float e  = expf(lg - mx);
        const float sm = wave_sum(e);
        sWt[l] = e / sm;                      // nt==0 -> NaN, guarded below
    }
    __syncthreads();

    const int nt = sNtok;
    float z = 0.f;
    if (nt > 0) {
        const float* base = vlog_ws + (size_t)b * (TLEN + 1) * D_MODEL;
        #pragma unroll 8
        for (int m = 0; m < MCON; ++m) {
            const float wm = sWt[m];          // 0 for m >= nt
            z += wm * base[(size_t)sVer[m] * D_MODEL + tid];
        }
    }
    y_ws[(size_t)token * D_MODEL + tid] = z;
}

// ---------------------------------------------------------------------------
// Kernel 4: out = y @ Wo + bo (unchanged — passed R2..R8).
// ---------------------------------------------------------------------------
__global__ __launch_bounds__(256) void out_kernel(
    const float* __restrict__ y_ws,
    const float* __restrict__ Wo, const float* __restrict__ bo,
    float* __restrict__ out)
{
    const int token = blockIdx.x;
    const int tid = threadIdx.x;
    __shared__ float sy[D_MODEL];
    sy[tid] = y_ws[token * D_MODEL + tid];
    __syncthreads();
    float acc = 0.f;
    #pragma unroll 8
    for (int i = 0; i < D_MODEL; ++i)
        acc += sy[i] * Wo[i * D_MODEL + tid];
    acc += bo[tid];
    out[token * D_MODEL + tid] = acc;
}

// ---------------------------------------------------------------------------
extern "C" void kernel_launch(void* const* d_in, const int* in_sizes, int n_in,
                              void* d_out, int out_size, void* d_ws, size_t ws_size,
                              hipStream_t stream)
{
    const float* x  = (const float*)d_in[0];
    const float* Wq = (const float*)d_in[1];
    const float* bq = (const float*)d_in[2];
    const float* Wk = (const float*)d_in[3];
    const float* bk = (const float*)d_in[4];
    const float* Wv = (const float*)d_in[5];
    const float* bv = (const float*)d_in[6];
    const float* Wo = (const float*)d_in[7];
    const float* bo = (const float*)d_in[8];
    const float* ls = (const float*)d_in[9];
    float* out = (float*)d_out;

    const int NTOK = BATCH * TLEN;                 // 4096
    char* ws = (char*)d_ws;
    size_t off = 0;
    float* q_ws    = (float*)(ws + off); off += (size_t)NTOK * D_STATE * 4;   // 1 MB
    float* k_ws    = (float*)(ws + off); off += (size_t)NTOK * D_STATE * 4;   // 1 MB
    float* v_ws    = (float*)(ws + off); off += (size_t)NTOK * D_MODEL * 4;   // 4 MB
    float* y_ws    = (float*)(ws + off); off += (size_t)NTOK * D_MODEL * 4;   // 4 MB
    float* sims_ws = (float*)(ws + off); off += (size_t)NTOK * MCON * 4;      // 1 MB
    int*   ver_ws  = (int*)  (ws + off); off += (size_t)NTOK * MCON * 4;      // 1 MB
    int*   n_ws    = (int*)  (ws + off); off += (size_t)NTOK * 4;             // 16 KB
    float* vlog_ws = (float*)(ws + off);                                      // 4.1 MB

    proj_kernel<<<NTOK, 256, 0, stream>>>(x, Wq, bq, Wk, bk, Wv, bv,
                                          q_ws, k_ws, v_ws);
    scan_kernel<<<BATCH, 64, 0, stream>>>(q_ws, k_ws, v_ws,
                                          sims_ws, n_ws, ver_ws, vlog_ws, ls);
    z_kernel<<<NTOK, 256, 0, stream>>>(sims_ws, n_ws, ver_ws, vlog_ws,
                                       y_ws, ls);
    out_kernel<<<NTOK, 256, 0, stream>>>(y_ws, Wo, bo, out);
}

// Round 11
// 1532.378 us; speedup vs baseline: 1.0485x; 1.0485x over previous
//
#include <hip/hip_runtime.h>
#include <hip/hip_bf16.h>

#define D_MODEL 256
#define D_STATE 64
#define MCON    64
#define TLEN    1024
#define BATCH   4
#define NEG_INF -1e9f
#define CSTRIDE 68

// ---------------- DPP wave-64 helpers ----------------
template <int CTRL, int RM>
__device__ __forceinline__ float dpp_f(float x) {
    int xi = __float_as_int(x);
    int r  = __builtin_amdgcn_update_dpp(xi, xi, CTRL, RM, 0xf, false);
    return __int_as_float(r);
}
template <int CTRL, int RM>
__device__ __forceinline__ int dpp_i(int x) {
    return __builtin_amdgcn_update_dpp(x, x, CTRL, RM, 0xf, false);
}
__device__ __forceinline__ float bcast_lane(float x, int lane) {
    return __int_as_float(__builtin_amdgcn_readlane(__float_as_int(x), lane));
}
__device__ __forceinline__ float wave_sum(float x) {
    x += dpp_f<0x111, 0xf>(x);
    x += dpp_f<0x112, 0xf>(x);
    x += dpp_f<0x114, 0xf>(x);
    x += dpp_f<0x118, 0xf>(x);
    x += dpp_f<0x142, 0xa>(x);
    x += dpp_f<0x143, 0xc>(x);
    return bcast_lane(x, 63);
}
__device__ __forceinline__ float wave_max(float x) {
    x = fmaxf(x, dpp_f<0x111, 0xf>(x));
    x = fmaxf(x, dpp_f<0x112, 0xf>(x));
    x = fmaxf(x, dpp_f<0x114, 0xf>(x));
    x = fmaxf(x, dpp_f<0x118, 0xf>(x));
    x = fmaxf(x, dpp_f<0x142, 0xa>(x));
    x = fmaxf(x, dpp_f<0x143, 0xc>(x));
    return bcast_lane(x, 63);
}
template <int CTRL, int RM>
__device__ __forceinline__ void maxarg_stage(float& v, int& i) {
    float ov = dpp_f<CTRL, RM>(v);
    int   oi = dpp_i<CTRL, RM>(i);
    const bool better = (ov > v) || (ov == v && oi < i);
    v = better ? ov : v;
    i = better ? oi : i;
}
// argmax over scores with first-index tiebreak (validated R8)
__device__ __forceinline__ int wave_argmax(float v, int lane) {
    int i = lane;
    maxarg_stage<0x111, 0xf>(v, i);
    maxarg_stage<0x112, 0xf>(v, i);
    maxarg_stage<0x114, 0xf>(v, i);
    maxarg_stage<0x118, 0xf>(v, i);
    maxarg_stage<0x142, 0xa>(v, i);
    maxarg_stage<0x143, 0xc>(v, i);
    return __builtin_amdgcn_readlane(i, 63);
}

// ---------------------------------------------------------------------------
// Kernel 1: per-token projections (unchanged — passed R2..R9).
// ---------------------------------------------------------------------------
__global__ __launch_bounds__(256) void proj_kernel(
    const float* __restrict__ x,
    const float* __restrict__ Wq, const float* __restrict__ bq,
    const float* __restrict__ Wk, const float* __restrict__ bk,
    const float* __restrict__ Wv, const float* __restrict__ bv,
    float* __restrict__ q_ws, float* __restrict__ k_ws, float* __restrict__ v_ws)
{
    const int token = blockIdx.x;
    const int tid = threadIdx.x;
    __shared__ float sx[D_MODEL];
    sx[tid] = x[token * D_MODEL + tid];
    __syncthreads();

    float acc = 0.f;
    #pragma unroll 8
    for (int i = 0; i < D_MODEL; ++i)
        acc += sx[i] * Wv[i * D_MODEL + tid];
    acc += bv[tid];
    v_ws[token * D_MODEL + tid] = acc;

    if (tid < 128) {
        const int j = tid & 63;
        const float* W  = (tid < 64) ? Wq : Wk;
        const float* bb = (tid < 64) ? bq : bk;
        float a = 0.f;
        #pragma unroll 8
        for (int i = 0; i < D_MODEL; ++i)
            a += sx[i] * W[i * D_STATE + j];
        a += bb[j];
        float s2 = a * a;
        #pragma unroll
        for (int off = 1; off < 64; off <<= 1) s2 += __shfl_xor(s2, off, 64);
        float nrm = fmaxf(sqrtf(s2), 1e-12f);
        float o = a / nrm;
        if (tid < 64) q_ws[token * D_STATE + j] = o;
        else          k_ws[token * D_STATE + j] = o;
    }
}

// ---------------------------------------------------------------------------
// Kernel 2: CONTROL scan — single wave, software-pipelined sims.
// sims_{t+1} bulk (all 64 rows vs pre-update C_t) issues at iter top and
// overlaps the control chain; only the one changed row is fixed up via
// speculative wave_sum dots. Zero barriers (same-wave DS program order).
// q broadcast by uniform-address float4 loads (no readlane chains - R9 lesson).
// ---------------------------------------------------------------------------
__global__ __launch_bounds__(64) void scan_kernel(
    const float* __restrict__ q_ws, const float* __restrict__ k_ws,
    const float* __restrict__ v_ws,
    float* __restrict__ sims_ws, int* __restrict__ n_ws,
    int* __restrict__ ver_ws, float* __restrict__ vlog_ws,
    const float* __restrict__ ls_p)
{
    const int b = blockIdx.x;
    const int l = threadIdx.x;          // lane 0..63
    const float scale = fminf(expf(ls_p[0]), 100.f);

    __shared__ __align__(16) float sCT[MCON * CSTRIDE];  // C rows, across-lane access
    __shared__ __align__(16) float sV[MCON * D_MODEL];   // 64 KB

    const float4 zero4 = make_float4(0.f, 0.f, 0.f, 0.f);
    for (int i = l; i < MCON * CSTRIDE; i += 64) sCT[i] = 0.f;
    #pragma unroll
    for (int i = 0; i < 64; ++i) ((float4*)sV)[i * 64 + l] = zero4;

    float cnt_l = 0.f;                  // counts[l] in lane l
    int   ver_l = 0;                    // version pointer for concept l
    int   n     = 0;                    // uniform
    float sim   = 0.f;                  // sims_0 vs zero C is exactly 0

    const float* qg = q_ws + b * TLEN * D_STATE;
    const float* kg = k_ws + b * TLEN * D_STATE;
    const float* vg = v_ws + b * TLEN * D_MODEL;
    float* vlog_b   = vlog_ws + (size_t)b * (TLEN + 1) * D_MODEL;

    *(float4*)&vlog_b[4 * l] = zero4;   // slot 0 = zeros

    // current-iter operands: k_0, v_0, q_1 (across-lane, for fixup dots)
    float  kv = kg[l];
    float4 vv = *(const float4*)&vg[4 * l];
    float  qv = qg[D_STATE + l];        // TLEN > 1

    for (int t = 0; t < TLEN; ++t) {
        const int token = b * TLEN + t;
        const int tq = (t + 1 < TLEN) ? t + 1 : t;   // q index for sims_{t+1}

        // ---- bulk reads of C_t row l (program order BEFORE this iter's C write)
        float4 cr[16];
        #pragma unroll
        for (int c = 0; c < 16; ++c) cr[c] = ((const float4*)sCT)[l * 17 + c];
        const float* qnx = qg + tq * D_STATE;        // uniform-address q_{t+1}

        // ---- logs (pre-update views; fire-and-forget)
        sims_ws[(size_t)token * MCON + l] = sim;
        ver_ws[(size_t)token * MCON + l]  = ver_l;
        if (l == 0) n_ws[token] = n;

        // ---- argmax over masked scores (semantics validated R8)
        const float lg = ((l < n) ? sim : NEG_INF) * scale;
        const int   sel    = wave_argmax(lg, l);
        const float selSim = bcast_lane(sim,   sel);
        const float cnt    = bcast_lane(cnt_l, sel);

        // ---- control DS reads
        const float  c_old = sCT[sel * CSTRIDE + l];
        const float4 vs    = *(const float4*)&sV[sel * D_MODEL + 4 * l];

        const float4 vt = vv;
        const float  kk = kv;

        // ---- residual (tree == R8)
        float r = (vs.x - vt.x) * (vs.x - vt.x)
                + (vs.y - vt.y) * (vs.y - vt.y)
                + (vs.z - vt.z) * (vs.z - vt.z)
                + (vs.w - vt.w) * (vs.w - vt.w);
        const float residual = sqrtf(wave_sum(r) * (1.f / 256.f));

        // ---- EMA candidate (speculative, parallel with residual)
        const float tmp  = 0.9f * c_old + 0.1f * kk;
        const float s2   = wave_sum(tmp * tmp);
        const float updc = tmp / fmaxf(sqrtf(s2), 1e-12f);

        // ---- speculative fixup dots for the changed row's next-step sim
        const float f_upd = wave_sum(updc * qv);
        const float f_add = wave_sum(kk   * qv);

        // ---- flags (uniform)
        const bool has       = n > 0;
        const bool refine    = has && (n < MCON) &&
                               (selSim < 0.75f || residual > 1.0f);
        const bool do_add    = ((!has) || refine) && (n < MCON);
        const bool do_update = has && !refine;
        const int  chg       = do_update ? sel : n;

        // ---- V update + vlog
        float4 nv;
        nv.x = (vs.x * cnt + vt.x) / (cnt + 1.f);
        nv.y = (vs.y * cnt + vt.y) / (cnt + 1.f);
        nv.z = (vs.z * cnt + vt.z) / (cnt + 1.f);
        nv.w = (vs.w * cnt + vt.w) / (cnt + 1.f);
        float4 valV;
        valV.x = do_update ? nv.x : vt.x;
        valV.y = do_update ? nv.y : vt.y;
        valV.z = do_update ? nv.z : vt.z;
        valV.w = do_update ? nv.w : vt.w;
        *(float4*)&sV[chg * D_MODEL + 4 * l] = valV;
        *(float4*)&vlog_b[(size_t)(t + 1) * D_MODEL + 4 * l] = valV;

        // ---- C update (across-lane write; bulk reads above saw C_t)
        const float newC = do_update ? updc : kk;
        sCT[chg * CSTRIDE + l] = newC;
        const float fsim = do_update ? f_upd : f_add;

        // ---- bulk FMAs: canonical (p0+p1)+(p2+p3) with 16-chains, j ascending
        float p0 = 0.f, p1 = 0.f, p2 = 0.f, p3 = 0.f;
        #pragma unroll
        for (int j = 0; j < 4; ++j) {
            const float4 q4 = *(const float4*)(qnx + 4 * j);
            p0 += cr[j].x * q4.x; p0 += cr[j].y * q4.y;
            p0 += cr[j].z * q4.z; p0 += cr[j].w * q4.w;
        }
        #pragma unroll
        for (int j = 0; j < 4; ++j) {
            const float4 q4 = *(const float4*)(qnx + 16 + 4 * j);
            p1 += cr[4 + j].x * q4.x; p1 += cr[4 + j].y * q4.y;
            p1 += cr[4 + j].z * q4.z; p1 += cr[4 + j].w * q4.w;
        }
        #pragma unroll
        for (int j = 0; j < 4; ++j) {
            const float4 q4 = *(const float4*)(qnx + 32 + 4 * j);
            p2 += cr[8 + j].x * q4.x; p2 += cr[8 + j].y * q4.y;
            p2 += cr[8 + j].z * q4.z; p2 += cr[8 + j].w * q4.w;
        }
        #pragma unroll
        for (int j = 0; j < 4; ++j) {
            const float4 q4 = *(const float4*)(qnx + 48 + 4 * j);
            p3 += cr[12 + j].x * q4.x; p3 += cr[12 + j].y * q4.y;
            p3 += cr[12 + j].z * q4.z; p3 += cr[12 + j].w * q4.w;
        }
        const float bulk = (p0 + p1) + (p2 + p3);
        sim = (l == chg) ? fsim : bulk;     // patch the one changed row

        // ---- counts / versions / n
        if (l == sel && do_update) cnt_l = cnt + 1.f;
        if (l == n   && do_add)    cnt_l = 1.f;
        if (l == chg) ver_l = t + 1;
        n += do_add ? 1 : 0;

        // ---- prefetch next-iter operands (k_{t+1}, v_{t+1}, q_{t+2})
        const int tk  = (t + 1 < TLEN) ? t + 1 : t;
        const int tq2 = (t + 2 < TLEN) ? t + 2 : TLEN - 1;
        kv = kg[tk * D_STATE + l];
        vv = *(const float4*)&vg[tk * D_MODEL + 4 * l];
        qv = qg[tq2 * D_STATE + l];
    }
}

// ---------------------------------------------------------------------------
// Kernel 3: PAYLOAD — parallel over tokens (unchanged — passed R8/R9).
// ---------------------------------------------------------------------------
__global__ __launch_bounds__(256) void z_kernel(
    const float* __restrict__ sims_ws, const int* __restrict__ n_ws,
    const int* __restrict__ ver_ws, const float* __restrict__ vlog_ws,
    float* __restrict__ y_ws, const float* __restrict__ ls_p)
{
    const int token = blockIdx.x;
    const int b     = token >> 10;           // TLEN = 1024
    const int tid   = threadIdx.x;
    const int l     = tid & 63;
    const int wv    = tid >> 6;
    const float scale = fminf(expf(ls_p[0]), 100.f);

    __shared__ float sWt[MCON];
    __shared__ int   sVer[MCON];
    __shared__ int   sNtok;

    if (tid == 0) sNtok = n_ws[token];
    if (wv == 1) sVer[l] = ver_ws[(size_t)token * MCON + l];
    if (wv == 0) {
        const float simv = sims_ws[(size_t)token * MCON + l];
        const int nt = n_ws[token];
        const float lg = ((l < nt) ? simv : NEG_INF) * scale;
        const float mx = wave_max(lg);
        const float e  = expf(lg - mx);
        const float sm = wave_sum(e);
        sWt[l] = e / sm;                      // nt==0 -> NaN, guarded below
    }
    __syncthreads();

    const int nt = sNtok;
    float z = 0.f;
    if (nt > 0) {
        const float* base = vlog_ws + (size_t)b * (TLEN + 1) * D_MODEL;
        #pragma unroll 8
        for (int m = 0; m < MCON; ++m) {
            const float wm = sWt[m];          // 0 for m >= nt
            z += wm * base[(size_t)sVer[m] * D_MODEL + tid];
        }
    }
    y_ws[(size_t)token * D_MODEL + tid] = z;
}

// ---------------------------------------------------------------------------
// Kernel 4: out = y @ Wo + bo (unchanged — passed R2..R9).
// ---------------------------------------------------------------------------
__global__ __launch_bounds__(256) void out_kernel(
    const float* __restrict__ y_ws,
    const float* __restrict__ Wo, const float* __restrict__ bo,
    float* __restrict__ out)
{
    const int token = blockIdx.x;
    const int tid = threadIdx.x;
    __shared__ float sy[D_MODEL];
    sy[tid] = y_ws[token * D_MODEL + tid];
    __syncthreads();
    float acc = 0.f;
    #pragma unroll 8
    for (int i = 0; i < D_MODEL; ++i)
        acc += sy[i] * Wo[i * D_MODEL + tid];
    acc += bo[tid];
    out[token * D_MODEL + tid] = acc;
}

// ---------------------------------------------------------------------------
extern "C" void kernel_launch(void* const* d_in, const int* in_sizes, int n_in,
                              void* d_out, int out_size, void* d_ws, size_t ws_size,
                              hipStream_t stream)
{
    const float* x  = (const float*)d_in[0];
    const float* Wq = (const float*)d_in[1];
    const float* bq = (const float*)d_in[2];
    const float* Wk = (const float*)d_in[3];
    const float* bk = (const float*)d_in[4];
    const float* Wv = (const float*)d_in[5];
    const float* bv = (const float*)d_in[6];
    const float* Wo = (const float*)d_in[7];
    const float* bo = (const float*)d_in[8];
    const float* ls = (const float*)d_in[9];
    float* out = (float*)d_out;

    const int NTOK = BATCH * TLEN;                 // 4096
    char* ws = (char*)d_ws;
    size_t off = 0;
    float* q_ws    = (float*)(ws + off); off += (size_t)NTOK * D_STATE * 4;   // 1 MB
    float* k_ws    = (float*)(ws + off); off += (size_t)NTOK * D_STATE * 4;   // 1 MB
    float* v_ws    = (float*)(ws + off); off += (size_t)NTOK * D_MODEL * 4;   // 4 MB
    float* y_ws    = (float*)(ws + off); off += (size_t)NTOK * D_MODEL * 4;   // 4 MB
    float* sims_ws = (float*)(ws + off); off += (size_t)NTOK * MCON * 4;      // 1 MB
    int*   ver_ws  = (int*)  (ws + off); off += (size_t)NTOK * MCON * 4;      // 1 MB
    int*   n_ws    = (int*)  (ws + off); off += (size_t)NTOK * 4;             // 16 KB
    float* vlog_ws = (float*)(ws + off);                                      // 4.1 MB

    proj_kernel<<<NTOK, 256, 0, stream>>>(x, Wq, bq, Wk, bk, Wv, bv,
                                          q_ws, k_ws, v_ws);
    scan_kernel<<<BATCH, 64, 0, stream>>>(q_ws, k_ws, v_ws,
                                          sims_ws, n_ws, ver_ws, vlog_ws, ls);
    z_kernel<<<NTOK, 256, 0, stream>>>(sims_ws, n_ws, ver_ws, vlog_ws,
                                       y_ws, ls);
    out_kernel<<<NTOK, 256, 0, stream>>>(y_ws, Wo, bo, out);
}

// Round 12
// 1445.895 us; speedup vs baseline: 1.1112x; 1.0598x over previous
//
#include <hip/hip_runtime.h>
#include <hip/hip_bf16.h>

#define D_MODEL 256
#define D_STATE 64
#define MCON    64
#define TLEN    1024
#define BATCH   4
#define NEG_INF -1e9f
#define CSTRIDE 68

// LDS-ordered workgroup barrier (no vmcnt drain; prefetch/log stores stay in flight)
#define BAR() asm volatile("s_waitcnt lgkmcnt(0)\n\ts_barrier" ::: "memory")

// ---------------- DPP wave-64 helpers ----------------
template <int CTRL, int RM>
__device__ __forceinline__ float dpp_f(float x) {
    int xi = __float_as_int(x);
    int r  = __builtin_amdgcn_update_dpp(xi, xi, CTRL, RM, 0xf, false);
    return __int_as_float(r);
}
template <int CTRL, int RM>
__device__ __forceinline__ int dpp_i(int x) {
    return __builtin_amdgcn_update_dpp(x, x, CTRL, RM, 0xf, false);
}
__device__ __forceinline__ float bcast_lane(float x, int lane) {
    return __int_as_float(__builtin_amdgcn_readlane(__float_as_int(x), lane));
}
__device__ __forceinline__ float wave_sum(float x) {
    x += dpp_f<0x111, 0xf>(x);
    x += dpp_f<0x112, 0xf>(x);
    x += dpp_f<0x114, 0xf>(x);
    x += dpp_f<0x118, 0xf>(x);
    x += dpp_f<0x142, 0xa>(x);
    x += dpp_f<0x143, 0xc>(x);
    return bcast_lane(x, 63);
}
__device__ __forceinline__ float wave_max(float x) {
    x = fmaxf(x, dpp_f<0x111, 0xf>(x));
    x = fmaxf(x, dpp_f<0x112, 0xf>(x));
    x = fmaxf(x, dpp_f<0x114, 0xf>(x));
    x = fmaxf(x, dpp_f<0x118, 0xf>(x));
    x = fmaxf(x, dpp_f<0x142, 0xa>(x));
    x = fmaxf(x, dpp_f<0x143, 0xc>(x));
    return bcast_lane(x, 63);
}
template <int CTRL, int RM>
__device__ __forceinline__ void maxarg_stage(float& v, int& i) {
    float ov = dpp_f<CTRL, RM>(v);
    int   oi = dpp_i<CTRL, RM>(i);
    const bool better = (ov > v) || (ov == v && oi < i);
    v = better ? ov : v;
    i = better ? oi : i;
}
// argmax over scores with first-index tiebreak (validated R8)
__device__ __forceinline__ int wave_argmax(float v, int lane) {
    int i = lane;
    maxarg_stage<0x111, 0xf>(v, i);
    maxarg_stage<0x112, 0xf>(v, i);
    maxarg_stage<0x114, 0xf>(v, i);
    maxarg_stage<0x118, 0xf>(v, i);
    maxarg_stage<0x142, 0xa>(v, i);
    maxarg_stage<0x143, 0xc>(v, i);
    return __builtin_amdgcn_readlane(i, 63);
}
// quad_perm [1,0,3,2] — swap adjacent lane pairs
__device__ __forceinline__ float dpp_swap1(float x) {
    int xi = __float_as_int(x);
    return __int_as_float(__builtin_amdgcn_update_dpp(xi, xi, 0xB1, 0xf, 0xf, false));
}

// ---------------------------------------------------------------------------
// Kernel 1: per-token projections (unchanged — passed R2..R11).
// ---------------------------------------------------------------------------
__global__ __launch_bounds__(256) void proj_kernel(
    const float* __restrict__ x,
    const float* __restrict__ Wq, const float* __restrict__ bq,
    const float* __restrict__ Wk, const float* __restrict__ bk,
    const float* __restrict__ Wv, const float* __restrict__ bv,
    float* __restrict__ q_ws, float* __restrict__ k_ws, float* __restrict__ v_ws)
{
    const int token = blockIdx.x;
    const int tid = threadIdx.x;
    __shared__ float sx[D_MODEL];
    sx[tid] = x[token * D_MODEL + tid];
    __syncthreads();

    float acc = 0.f;
    #pragma unroll 8
    for (int i = 0; i < D_MODEL; ++i)
        acc += sx[i] * Wv[i * D_MODEL + tid];
    acc += bv[tid];
    v_ws[token * D_MODEL + tid] = acc;

    if (tid < 128) {
        const int j = tid & 63;
        const float* W  = (tid < 64) ? Wq : Wk;
        const float* bb = (tid < 64) ? bq : bk;
        float a = 0.f;
        #pragma unroll 8
        for (int i = 0; i < D_MODEL; ++i)
            a += sx[i] * W[i * D_STATE + j];
        a += bb[j];
        float s2 = a * a;
        #pragma unroll
        for (int off = 1; off < 64; off <<= 1) s2 += __shfl_xor(s2, off, 64);
        float nrm = fmaxf(sqrtf(s2), 1e-12f);
        float o = a / nrm;
        if (tid < 64) q_ws[token * D_STATE + j] = o;
        else          k_ws[token * D_STATE + j] = o;
    }
}

// ---------------------------------------------------------------------------
// Kernel 2: CONTROL scan — 4 waves, pipelined sims.
//  waves 2,3: bulk sims_{t+1} = C_t · q_{t+1} (2 lanes/row, bit-identical tree)
//             into double-buffered sBuf, overlapping the control chain.
//  wave 1:    control chain (argmax -> LDS -> residual/EMA/fixup -> flags),
//             register patch of the one changed row, logs, C/V updates.
//  wave 0:    q staging into double-buffered sQ.
// 2 lgkm-only barriers/step. All branch-feeding trees bit-identical to R8/R10.
// ---------------------------------------------------------------------------
__global__ __launch_bounds__(256) void scan_kernel(
    const float* __restrict__ q_ws, const float* __restrict__ k_ws,
    const float* __restrict__ v_ws,
    float* __restrict__ sims_ws, int* __restrict__ n_ws,
    int* __restrict__ ver_ws, float* __restrict__ vlog_ws,
    const float* __restrict__ ls_p)
{
    const int b   = blockIdx.x;
    const int tid = threadIdx.x;
    const int l   = tid & 63;
    const int wv  = tid >> 6;
    const float scale = fminf(expf(ls_p[0]), 100.f);

    __shared__ __align__(16) float sCT[MCON * CSTRIDE];  // 17.4 KB centroids
    __shared__ __align__(16) float sV[MCON * D_MODEL];   // 64 KB values
    __shared__ __align__(16) float sQ[2][D_STATE];       // staged q (dbuf)
    __shared__ __align__(16) float sBuf[2][MCON];        // sims buffer (dbuf)

    // ---- init ----
    const float4 zero4 = make_float4(0.f, 0.f, 0.f, 0.f);
    for (int i = tid; i < MCON * CSTRIDE; i += 256) sCT[i] = 0.f;
    #pragma unroll
    for (int i = 0; i < 16; ++i) ((float4*)sV)[i * 256 + tid] = zero4;
    if (tid < MCON) sBuf[0][tid] = 0.f;    // sims_0 (C=0)

    const float* qg = q_ws + b * TLEN * D_STATE;
    const float* kg = k_ws + b * TLEN * D_STATE;
    const float* vg = v_ws + b * TLEN * D_MODEL;
    float* vlog_b   = vlog_ws + (size_t)b * (TLEN + 1) * D_MODEL;

    if (tid < 64) *(float4*)&vlog_b[4 * l] = zero4;   // vlog slot 0 = zeros

    // wave 0: stage q_1 into sQ[1] (bulk at t=0 reads it); prefetch q_2
    float qstage = 0.f;
    if (wv == 0) {
        sQ[1][l] = qg[D_STATE + l];          // q_1 (TLEN > 1)
        qstage   = qg[2 * D_STATE + l];      // q_2
    }

    // wave 1 state
    float cnt_l = 0.f;     // counts[l]
    int   ver_l = 0;       // version pointer for concept l
    int   n     = 0;
    int   chg_prev = -1;
    float fsim_prev = 0.f;
    float kk = 0.f, qv = 0.f;
    float4 vvt = zero4;
    if (wv == 1) {
        kk  = kg[l];                          // k_0
        vvt = *(const float4*)&vg[4 * l];     // v_0
        qv  = qg[D_STATE + l];                // q_1 (for fixup dots at t=0)
    }

    // bulk lane mapping (waves 2,3): 2 lanes per row
    const int brow = ((wv - 2) << 5) + (l >> 1);   // valid for wv>=2
    const int bh   = l & 1;                        // half: 0 -> parts 0,1; 1 -> parts 2,3

    __syncthreads();   // init visible

    for (int t = 0; t < TLEN; ++t) {
        const int token = b * TLEN + t;
        const int pc = t & 1;          // current sims parity
        const int pn = 1 - pc;         // next sims parity

        if (wv >= 2) {
            // ---- bulk sims_{t+1}[brow] = C_t[brow] . q_{t+1} ----
            const float* crow = &sCT[brow * CSTRIDE + 32 * bh];
            const float* qrow = &sQ[pn][32 * bh];
            float pa = 0.f, pb = 0.f;
            #pragma unroll
            for (int c = 0; c < 4; ++c) {       // first 16-chain (ascending)
                const float4 c4 = *(const float4*)(crow + 4 * c);
                const float4 q4 = *(const float4*)(qrow + 4 * c);
                pa += c4.x * q4.x; pa += c4.y * q4.y;
                pa += c4.z * q4.z; pa += c4.w * q4.w;
            }
            #pragma unroll
            for (int c = 4; c < 8; ++c) {       // second 16-chain
                const float4 c4 = *(const float4*)(crow + 4 * c);
                const float4 q4 = *(const float4*)(qrow + 4 * c);
                pb += c4.x * q4.x; pb += c4.y * q4.y;
                pb += c4.z * q4.z; pb += c4.w * q4.w;
            }
            const float s   = pa + pb;          // (p0+p1) on h=0, (p2+p3) on h=1
            const float sim = s + dpp_swap1(s); // h=0 lane: (p0+p1)+(p2+p3)
            if (bh == 0) sBuf[pn][brow] = sim;
        }

        if (wv == 0) {
            // ---- stage q_{t+2} into sQ[pc] (read by bulk at t+1) ----
            sQ[pc][l] = qstage;
            const int tq3 = (t + 3 < TLEN) ? t + 3 : TLEN - 1;
            qstage = qg[tq3 * D_STATE + l];
        }

        // wave-1 control chain (pre-B1: reads only)
        float newC = 0.f; float4 valV = zero4;
        int   sel = 0, chg = 0;
        bool  do_add = false, do_update = false;
        float cnt = 0.f, fsim = 0.f;
        if (wv == 1) {
            const float bufv = sBuf[pc][l];
            const float simv = (l == chg_prev) ? fsim_prev : bufv;

            // logs (pre-update views; fire-and-forget global stores)
            sims_ws[(size_t)token * MCON + l] = simv;
            ver_ws[(size_t)token * MCON + l]  = ver_l;
            if (l == 0) n_ws[token] = n;

            // f_add is chain-independent — issue early
            const float f_add = wave_sum(kk * qv);

            const float lg = ((l < n) ? simv : NEG_INF) * scale;
            sel = wave_argmax(lg, l);
            const float selSim = bcast_lane(simv,  sel);
            cnt = bcast_lane(cnt_l, sel);

            const float  c_old = sCT[sel * CSTRIDE + l];
            const float4 vs    = *(const float4*)&sV[sel * D_MODEL + 4 * l];
            const float4 vt    = vvt;

            float r = (vs.x - vt.x) * (vs.x - vt.x)
                    + (vs.y - vt.y) * (vs.y - vt.y)
                    + (vs.z - vt.z) * (vs.z - vt.z)
                    + (vs.w - vt.w) * (vs.w - vt.w);
            const float residual = sqrtf(wave_sum(r) * (1.f / 256.f));

            const float tmp  = 0.9f * c_old + 0.1f * kk;
            const float s2   = wave_sum(tmp * tmp);
            const float updc = tmp / fmaxf(sqrtf(s2), 1e-12f);
            const float f_upd = wave_sum(updc * qv);

            const bool has = n > 0;
            const bool refine = has && (n < MCON) &&
                                (selSim < 0.75f || residual > 1.0f);
            do_add    = ((!has) || refine) && (n < MCON);
            do_update = has && !refine;
            chg  = do_update ? sel : n;
            fsim = do_update ? f_upd : f_add;
            newC = do_update ? updc : kk;

            float4 nv;
            nv.x = (vs.x * cnt + vt.x) / (cnt + 1.f);
            nv.y = (vs.y * cnt + vt.y) / (cnt + 1.f);
            nv.z = (vs.z * cnt + vt.z) / (cnt + 1.f);
            nv.w = (vs.w * cnt + vt.w) / (cnt + 1.f);
            valV.x = do_update ? nv.x : vt.x;
            valV.y = do_update ? nv.y : vt.y;
            valV.z = do_update ? nv.z : vt.z;
            valV.w = do_update ? nv.w : vt.w;

            // V update: bulk never touches sV -> safe pre-B1 (same-wave order
            // guarantees our vs read precedes this write)
            *(float4*)&sV[chg * D_MODEL + 4 * l] = valV;
            *(float4*)&vlog_b[(size_t)(t + 1) * D_MODEL + 4 * l] = valV;

            // prefetch next-step operands (slack ~= rest of step)
            const int tk  = (t + 1 < TLEN) ? t + 1 : t;
            const int tq2 = (t + 2 < TLEN) ? t + 2 : TLEN - 1;
            kk  = kg[tk * D_STATE + l];
            vvt = *(const float4*)&vg[tk * D_MODEL + 4 * l];
            qv  = qg[tq2 * D_STATE + l];
        }

        BAR();   // B1: bulk's C reads complete before wave1's C write

        if (wv == 1) {
            sCT[chg * CSTRIDE + l] = newC;       // post-B1 C write
            if (l == sel && do_update) cnt_l = cnt + 1.f;
            if (l == n   && do_add)    cnt_l = 1.f;
            if (l == chg) ver_l = t + 1;
            n += do_add ? 1 : 0;
            chg_prev  = chg;
            fsim_prev = fsim;
        }

        BAR();   // B2: C write + bulk sBuf stores visible for next step
    }
}

// ---------------------------------------------------------------------------
// Kernel 3: PAYLOAD — parallel over tokens (unchanged — passed R8..R11).
// ---------------------------------------------------------------------------
__global__ __launch_bounds__(256) void z_kernel(
    const float* __restrict__ sims_ws, const int* __restrict__ n_ws,
    const int* __restrict__ ver_ws, const float* __restrict__ vlog_ws,
    float* __restrict__ y_ws, const float* __restrict__ ls_p)
{
    const int token = blockIdx.x;
    const int b     = token >> 10;           // TLEN = 1024
    const int tid   = threadIdx.x;
    const int l     = tid & 63;
    const int wv    = tid >> 6;
    const float scale = fminf(expf(ls_p[0]), 100.f);

    __shared__ float sWt[MCON];
    __shared__ int   sVer[MCON];
    __shared__ int   sNtok;

    if (tid == 0) sNtok = n_ws[token];
    if (wv == 1) sVer[l] = ver_ws[(size_t)token * MCON + l];
    if (wv == 0) {
        const float simv = sims_ws[(size_t)token * MCON + l];
        const int nt = n_ws[token];
        const float lg = ((l < nt) ? simv : NEG_INF) * scale;
        const float mx = wave_max(lg);
        const float e  = expf(lg - mx);
        const float sm = wave_sum(e);
        sWt[l] = e / sm;                      // nt==0 -> NaN, guarded below
    }
    __syncthreads();

    const int nt = sNtok;
    float z = 0.f;
    if (nt > 0) {
        const float* base = vlog_ws + (size_t)b * (TLEN + 1) * D_MODEL;
        #pragma unroll 8
        for (int m = 0; m < MCON; ++m) {
            const float wm = sWt[m];          // 0 for m >= nt
            z += wm * base[(size_t)sVer[m] * D_MODEL + tid];
        }
    }
    y_ws[(size_t)token * D_MODEL + tid] = z;
}

// ---------------------------------------------------------------------------
// Kernel 4: out = y @ Wo + bo (unchanged — passed R2..R11).
// ---------------------------------------------------------------------------
__global__ __launch_bounds__(256) void out_kernel(
    const float* __restrict__ y_ws,
    const float* __restrict__ Wo, const float* __restrict__ bo,
    float* __restrict__ out)
{
    const int token = blockIdx.x;
    const int tid = threadIdx.x;
    __shared__ float sy[D_MODEL];
    sy[tid] = y_ws[token * D_MODEL + tid];
    __syncthreads();
    float acc = 0.f;
    #pragma unroll 8
    for (int i = 0; i < D_MODEL; ++i)
        acc += sy[i] * Wo[i * D_MODEL + tid];
    acc += bo[tid];
    out[token * D_MODEL + tid] = acc;
}

// ---------------------------------------------------------------------------
extern "C" void kernel_launch(void* const* d_in, const int* in_sizes, int n_in,
                              void* d_out, int out_size, void* d_ws, size_t ws_size,
                              hipStream_t stream)
{
    const float* x  = (const float*)d_in[0];
    const float* Wq = (const float*)d_in[1];
    const float* bq = (const float*)d_in[2];
    const float* Wk = (const float*)d_in[3];
    const float* bk = (const float*)d_in[4];
    const float* Wv = (const float*)d_in[5];
    const float* bv = (const float*)d_in[6];
    const float* Wo = (const float*)d_in[7];
    const float* bo = (const float*)d_in[8];
    const float* ls = (const float*)d_in[9];
    float* out = (float*)d_out;

    const int NTOK = BATCH * TLEN;                 // 4096
    char* ws = (char*)d_ws;
    size_t off = 0;
    float* q_ws    = (float*)(ws + off); off += (size_t)NTOK * D_STATE * 4;   // 1 MB
    float* k_ws    = (float*)(ws + off); off += (size_t)NTOK * D_STATE * 4;   // 1 MB
    float* v_ws    = (float*)(ws + off); off += (size_t)NTOK * D_MODEL * 4;   // 4 MB
    float* y_ws    = (float*)(ws + off); off += (size_t)NTOK * D_MODEL * 4;   // 4 MB
    float* sims_ws = (float*)(ws + off); off += (size_t)NTOK * MCON * 4;      // 1 MB
    int*   ver_ws  = (int*)  (ws + off); off += (size_t)NTOK * MCON * 4;      // 1 MB
    int*   n_ws    = (int*)  (ws + off); off += (size_t)NTOK * 4;             // 16 KB
    float* vlog_ws = (float*)(ws + off);                                      // 4.1 MB

    proj_kernel<<<NTOK, 256, 0, stream>>>(x, Wq, bq, Wk, bk, Wv, bv,
                                          q_ws, k_ws, v_ws);
    scan_kernel<<<BATCH, 256, 0, stream>>>(q_ws, k_ws, v_ws,
                                           sims_ws, n_ws, ver_ws, vlog_ws, ls);
    z_kernel<<<NTOK, 256, 0, stream>>>(sims_ws, n_ws, ver_ws, vlog_ws,
                                       y_ws, ls);
    out_kernel<<<NTOK, 256, 0, stream>>>(y_ws, Wo, bo, out);
}

// Round 13
// 1172.222 us; speedup vs baseline: 1.3706x; 1.2335x over previous
//
#include <hip/hip_runtime.h>
#include <hip/hip_bf16.h>

#define D_MODEL 256
#define D_STATE 64
#define MCON    64
#define TLEN    1024
#define BATCH   4
#define NEG_INF -1e9f
#define CSTRIDE 68

// LDS-ordered workgroup barrier (no vmcnt drain)
#define BAR() asm volatile("s_waitcnt lgkmcnt(0)\n\ts_barrier" ::: "memory")

// ---------------- DPP wave-64 helpers ----------------
template <int CTRL, int RM>
__device__ __forceinline__ float dpp_f(float x) {
    int xi = __float_as_int(x);
    int r  = __builtin_amdgcn_update_dpp(xi, xi, CTRL, RM, 0xf, false);
    return __int_as_float(r);
}
template <int CTRL, int RM>
__device__ __forceinline__ int dpp_i(int x) {
    return __builtin_amdgcn_update_dpp(x, x, CTRL, RM, 0xf, false);
}
__device__ __forceinline__ float bcast_lane(float x, int lane) {
    return __int_as_float(__builtin_amdgcn_readlane(__float_as_int(x), lane));
}
__device__ __forceinline__ float wave_sum(float x) {
    x += dpp_f<0x111, 0xf>(x);
    x += dpp_f<0x112, 0xf>(x);
    x += dpp_f<0x114, 0xf>(x);
    x += dpp_f<0x118, 0xf>(x);
    x += dpp_f<0x142, 0xa>(x);
    x += dpp_f<0x143, 0xc>(x);
    return bcast_lane(x, 63);
}
__device__ __forceinline__ float wave_max(float x) {
    x = fmaxf(x, dpp_f<0x111, 0xf>(x));
    x = fmaxf(x, dpp_f<0x112, 0xf>(x));
    x = fmaxf(x, dpp_f<0x114, 0xf>(x));
    x = fmaxf(x, dpp_f<0x118, 0xf>(x));
    x = fmaxf(x, dpp_f<0x142, 0xa>(x));
    x = fmaxf(x, dpp_f<0x143, 0xc>(x));
    return bcast_lane(x, 63);
}
template <int CTRL, int RM>
__device__ __forceinline__ void maxarg_stage(float& v, int& i) {
    float ov = dpp_f<CTRL, RM>(v);
    int   oi = dpp_i<CTRL, RM>(i);
    const bool better = (ov > v) || (ov == v && oi < i);
    v = better ? ov : v;
    i = better ? oi : i;
}
__device__ __forceinline__ int wave_argmax(float v, int lane) {
    int i = lane;
    maxarg_stage<0x111, 0xf>(v, i);
    maxarg_stage<0x112, 0xf>(v, i);
    maxarg_stage<0x114, 0xf>(v, i);
    maxarg_stage<0x118, 0xf>(v, i);
    maxarg_stage<0x142, 0xa>(v, i);
    maxarg_stage<0x143, 0xc>(v, i);
    return __builtin_amdgcn_readlane(i, 63);
}
// quad_perm [1,0,3,2] — swap adjacent lane pairs
__device__ __forceinline__ float dpp_swap1(float x) {
    int xi = __float_as_int(x);
    return __int_as_float(__builtin_amdgcn_update_dpp(xi, xi, 0xB1, 0xf, 0xf, false));
}

// ---------------------------------------------------------------------------
// Kernel 1: per-token projections (unchanged — passed R2..R12).
// ---------------------------------------------------------------------------
__global__ __launch_bounds__(256) void proj_kernel(
    const float* __restrict__ x,
    const float* __restrict__ Wq, const float* __restrict__ bq,
    const float* __restrict__ Wk, const float* __restrict__ bk,
    const float* __restrict__ Wv, const float* __restrict__ bv,
    float* __restrict__ q_ws, float* __restrict__ k_ws, float* __restrict__ v_ws)
{
    const int token = blockIdx.x;
    const int tid = threadIdx.x;
    __shared__ float sx[D_MODEL];
    sx[tid] = x[token * D_MODEL + tid];
    __syncthreads();

    float acc = 0.f;
    #pragma unroll 8
    for (int i = 0; i < D_MODEL; ++i)
        acc += sx[i] * Wv[i * D_MODEL + tid];
    acc += bv[tid];
    v_ws[token * D_MODEL + tid] = acc;

    if (tid < 128) {
        const int j = tid & 63;
        const float* W  = (tid < 64) ? Wq : Wk;
        const float* bb = (tid < 64) ? bq : bk;
        float a = 0.f;
        #pragma unroll 8
        for (int i = 0; i < D_MODEL; ++i)
            a += sx[i] * W[i * D_STATE + j];
        a += bb[j];
        float s2 = a * a;
        #pragma unroll
        for (int off = 1; off < 64; off <<= 1) s2 += __shfl_xor(s2, off, 64);
        float nrm = fmaxf(sqrtf(s2), 1e-12f);
        float o = a / nrm;
        if (tid < 64) q_ws[token * D_STATE + j] = o;
        else          k_ws[token * D_STATE + j] = o;
    }
}

// ---------------------------------------------------------------------------
// Kernel 2: CONTROL scan — 4 waves, 1 barrier/step.
//  waves 2,3 (bulk): own 32 C rows each (2 lanes/row). Per step: write back
//    last step's changed row (same-wave order), then compute
//    bulkdot_m = C_t[m]·q_{t+1}, tmp_m = 0.9C+0.1k_t, s2_m = sum(tmp²).
//    tmp/k kept in registers for next step's write-back.
//  wave 1 (control): patch sims via linearity (no EMA on chain), argmax,
//    V[sel] read, residual, flags, V/count/ver updates, publish flags.
//  wave 0: q/k staging + f_add = ws(k_t·q_{t+1}).
// All cross-wave handoffs are step-to-step through double buffers -> 1 BAR.
// ---------------------------------------------------------------------------
__global__ __launch_bounds__(256) void scan_kernel(
    const float* __restrict__ q_ws, const float* __restrict__ k_ws,
    const float* __restrict__ v_ws,
    float* __restrict__ sims_ws, int* __restrict__ n_ws,
    int* __restrict__ ver_ws, float* __restrict__ vlog_ws,
    const float* __restrict__ ls_p)
{
    const int b   = blockIdx.x;
    const int tid = threadIdx.x;
    const int l   = tid & 63;
    const int wv  = tid >> 6;
    const float scale = fminf(expf(ls_p[0]), 100.f);

    __shared__ __align__(16) float sCT[MCON * CSTRIDE];  // centroids
    __shared__ __align__(16) float sV[MCON * D_MODEL];   // values (wave1 only)
    __shared__ __align__(16) float sQ[2][D_STATE];
    __shared__ __align__(16) float sK[2][D_STATE];
    __shared__ __align__(16) float sBuf[2][MCON];        // bulkdot (sims_{t+1})
    __shared__ __align__(16) float sS2[2][MCON];         // sum(tmp^2) per row
    __shared__ float sFA[2];                             // f_add = k_t . q_{t+1}
    __shared__ int   sFlagChg[2];
    __shared__ int   sFlagUpd[2];

    // ---- init ----
    const float4 zero4 = make_float4(0.f, 0.f, 0.f, 0.f);
    for (int i = tid; i < MCON * CSTRIDE; i += 256) sCT[i] = 0.f;
    #pragma unroll
    for (int i = 0; i < 16; ++i) ((float4*)sV)[i * 256 + tid] = zero4;
    if (tid < MCON) { sBuf[0][tid] = 0.f; sS2[0][tid] = 0.f; }
    if (tid == 0) { sFA[0] = 0.f; sFlagChg[0] = -1; sFlagUpd[0] = 0; }

    const float* qg = q_ws + b * TLEN * D_STATE;
    const float* kg = k_ws + b * TLEN * D_STATE;
    const float* vg = v_ws + b * TLEN * D_MODEL;
    float* vlog_b   = vlog_ws + (size_t)b * (TLEN + 1) * D_MODEL;

    if (tid < 64) {
        *(float4*)&vlog_b[4 * l] = zero4;   // vlog slot 0 = zeros
        sQ[1][l] = qg[D_STATE + l];         // q_1 (TLEN > 1)
        sK[0][l] = kg[l];                   // k_0
    }

    // ---- per-wave persistent state ----
    // wave 0
    float qcur = 0.f, kcur = 0.f, qnx2 = 0.f, knx = 0.f;
    if (wv == 0) {
        kcur = kg[l];                        // k_0
        qcur = qg[D_STATE + l];              // q_1
        knx  = kg[D_STATE + l];              // k_1
        qnx2 = qg[2 * D_STATE + l];          // q_2
    }
    // wave 1
    float  cnt_l = 0.f;
    int    ver_l = 0, n = 0, chg_prev = -1, upd_prev = 0;
    float4 vvt = zero4;
    if (wv == 1) vvt = *(const float4*)&vg[4 * l];   // v_0
    // bulk waves: row ownership + retained tmp/k/s2 for write-back
    const int brow = ((wv - 2) << 5) + (l >> 1);     // valid wv>=2
    const int bh   = l & 1;
    float4 tprev[8], kprev[8];
    float  s2prev = 0.f;
    #pragma unroll
    for (int c = 0; c < 8; ++c) { tprev[c] = zero4; kprev[c] = zero4; }

    __syncthreads();   // init visible

    for (int t = 0; t < TLEN; ++t) {
        const int token = b * TLEN + t;
        const int pc = t & 1, pn = 1 - pc;

        if (wv >= 2) {
            // ---- 1) write back last step's changed row (if owned) ----
            const int chg  = sFlagChg[pc];
            const int updf = sFlagUpd[pc];
            if (chg == brow) {
                const float rn = 1.f / fmaxf(sqrtf(s2prev), 1e-12f);
                float* dst = &sCT[brow * CSTRIDE + 32 * bh];
                #pragma unroll
                for (int c = 0; c < 8; ++c) {
                    float4 o;
                    o.x = updf ? tprev[c].x * rn : kprev[c].x;
                    o.y = updf ? tprev[c].y * rn : kprev[c].y;
                    o.z = updf ? tprev[c].z * rn : kprev[c].z;
                    o.w = updf ? tprev[c].w * rn : kprev[c].w;
                    *(float4*)(dst + 4 * c) = o;
                }
            }
            // ---- 2) bulk: dot, tmp, s2 (reads own rows post-write) ----
            const float* crow = &sCT[brow * CSTRIDE + 32 * bh];
            const float* qrow = &sQ[pn][32 * bh];
            const float* krow = &sK[pc][32 * bh];
            float pa = 0.f, pb = 0.f, sa = 0.f, sb = 0.f;
            #pragma unroll
            for (int c = 0; c < 8; ++c) {
                const float4 c4 = *(const float4*)(crow + 4 * c);
                const float4 q4 = *(const float4*)(qrow + 4 * c);
                const float4 k4 = *(const float4*)(krow + 4 * c);
                float4 t4;
                t4.x = 0.9f * c4.x + 0.1f * k4.x;
                t4.y = 0.9f * c4.y + 0.1f * k4.y;
                t4.z = 0.9f * c4.z + 0.1f * k4.z;
                t4.w = 0.9f * c4.w + 0.1f * k4.w;
                if (c < 4) {
                    pa += c4.x * q4.x; pa += c4.y * q4.y;
                    pa += c4.z * q4.z; pa += c4.w * q4.w;
                    sa += t4.x * t4.x; sa += t4.y * t4.y;
                    sa += t4.z * t4.z; sa += t4.w * t4.w;
                } else {
                    pb += c4.x * q4.x; pb += c4.y * q4.y;
                    pb += c4.z * q4.z; pb += c4.w * q4.w;
                    sb += t4.x * t4.x; sb += t4.y * t4.y;
                    sb += t4.z * t4.z; sb += t4.w * t4.w;
                }
                tprev[c] = t4; kprev[c] = k4;
            }
            const float sd = pa + pb;               // (p0+p1) / (p2+p3)
            const float dot = sd + dpp_swap1(sd);   // full row dot (both lanes)
            const float ss = sa + sb;
            const float s2 = ss + dpp_swap1(ss);    // full row s2 (both lanes)
            s2prev = s2;
            if (bh == 0) { sBuf[pn][brow] = dot; sS2[pn][brow] = s2; }
        }

        if (wv == 0) {
            // stage q_{t+2} -> sQ[pc], k_{t+1} -> sK[pn]; f_add off-chain
            sQ[pc][l] = qnx2;
            sK[pn][l] = knx;
            const float fa = wave_sum(kcur * qcur);  // k_t . q_{t+1}
            if (l == 0) sFA[pn] = fa;
            kcur = knx; qcur = qnx2;
            const int tk2 = (t + 2 < TLEN) ? t + 2 : TLEN - 1;
            const int tq3 = (t + 3 < TLEN) ? t + 3 : TLEN - 1;
            knx  = kg[tk2 * D_STATE + l];
            qnx2 = qg[tq3 * D_STATE + l];
        }

        if (wv == 1) {
            // ---- patched sims via linearity (no EMA on chain) ----
            const int   ip   = (chg_prev < 0) ? 0 : chg_prev;
            const float bufv = sBuf[pc][l];
            const float s2v  = sS2[pc][ip];
            const float fa   = sFA[pc];
            const float bdc  = bcast_lane(bufv, ip);
            const float fupd = (0.9f * bdc + 0.1f * fa)
                               / fmaxf(sqrtf(s2v), 1e-12f);
            const float fsim = upd_prev ? fupd : fa;
            const float simv = (l == chg_prev) ? fsim : bufv;

            // logs (pre-update views)
            sims_ws[(size_t)token * MCON + l] = simv;
            ver_ws[(size_t)token * MCON + l]  = ver_l;
            if (l == 0) n_ws[token] = n;

            // argmax chain
            const float lg = ((l < n) ? simv : NEG_INF) * scale;
            const int   sel    = wave_argmax(lg, l);
            const float selSim = bcast_lane(simv,  sel);
            const float cnt    = bcast_lane(cnt_l, sel);

            const float4 vs = *(const float4*)&sV[sel * D_MODEL + 4 * l];
            const float4 vt = vvt;
            float r = (vs.x - vt.x) * (vs.x - vt.x)
                    + (vs.y - vt.y) * (vs.y - vt.y)
                    + (vs.z - vt.z) * (vs.z - vt.z)
                    + (vs.w - vt.w) * (vs.w - vt.w);
            const float residual = sqrtf(wave_sum(r) * (1.f / 256.f));

            const bool has = n > 0;
            const bool refine = has && (n < MCON) &&
                                (selSim < 0.75f || residual > 1.0f);
            const bool do_add    = ((!has) || refine) && (n < MCON);
            const bool do_update = has && !refine;
            const int  chg = do_update ? sel : n;

            float4 nv;
            nv.x = (vs.x * cnt + vt.x) / (cnt + 1.f);
            nv.y = (vs.y * cnt + vt.y) / (cnt + 1.f);
            nv.z = (vs.z * cnt + vt.z) / (cnt + 1.f);
            nv.w = (vs.w * cnt + vt.w) / (cnt + 1.f);
            float4 valV;
            valV.x = do_update ? nv.x : vt.x;
            valV.y = do_update ? nv.y : vt.y;
            valV.z = do_update ? nv.z : vt.z;
            valV.w = do_update ? nv.w : vt.w;
            *(float4*)&sV[chg * D_MODEL + 4 * l] = valV;     // same-wave order
            *(float4*)&vlog_b[(size_t)(t + 1) * D_MODEL + 4 * l] = valV;

            // publish flags for bulk's next-step write-back
            if (l == 0) { sFlagChg[pn] = chg; sFlagUpd[pn] = do_update ? 1 : 0; }

            if (l == sel && do_update) cnt_l = cnt + 1.f;
            if (l == n   && do_add)    cnt_l = 1.f;
            if (l == chg) ver_l = t + 1;
            n += do_add ? 1 : 0;
            chg_prev = chg; upd_prev = do_update ? 1 : 0;

            // prefetch v_{t+1}
            const int tk = (t + 1 < TLEN) ? t + 1 : t;
            vvt = *(const float4*)&vg[tk * D_MODEL + 4 * l];
        }

        BAR();   // single per-step barrier: all dbuf handoffs publish here
    }
}

// ---------------------------------------------------------------------------
// Kernel 3: PAYLOAD — parallel over tokens (unchanged — passed R8..R12).
// ---------------------------------------------------------------------------
__global__ __launch_bounds__(256) void z_kernel(
    const float* __restrict__ sims_ws, const int* __restrict__ n_ws,
    const int* __restrict__ ver_ws, const float* __restrict__ vlog_ws,
    float* __restrict__ y_ws, const float* __restrict__ ls_p)
{
    const int token = blockIdx.x;
    const int b     = token >> 10;           // TLEN = 1024
    const int tid   = threadIdx.x;
    const int l     = tid & 63;
    const int wv    = tid >> 6;
    const float scale = fminf(expf(ls_p[0]), 100.f);

    __shared__ float sWt[MCON];
    __shared__ int   sVer[MCON];
    __shared__ int   sNtok;

    if (tid == 0) sNtok = n_ws[token];
    if (wv == 1) sVer[l] = ver_ws[(size_t)token * MCON + l];
    if (wv == 0) {
        const float simv = sims_ws[(size_t)token * MCON + l];
        const int nt = n_ws[token];
        const float lg = ((l < nt) ? simv : NEG_INF) * scale;
        const float mx = wave_max(lg);
        const float e  = expf(lg - mx);
        const float sm = wave_sum(e);
        sWt[l] = e / sm;                      // nt==0 -> NaN, guarded below
    }
    __syncthreads();

    const int nt = sNtok;
    float z = 0.f;
    if (nt > 0) {
        const float* base = vlog_ws + (size_t)b * (TLEN + 1) * D_MODEL;
        #pragma unroll 8
        for (int m = 0; m < MCON; ++m) {
            const float wm = sWt[m];          // 0 for m >= nt
            z += wm * base[(size_t)sVer[m] * D_MODEL + tid];
        }
    }
    y_ws[(size_t)token * D_MODEL + tid] = z;
}

// ---------------------------------------------------------------------------
// Kernel 4: out = y @ Wo + bo (unchanged — passed R2..R12).
// ---------------------------------------------------------------------------
__global__ __launch_bounds__(256) void out_kernel(
    const float* __restrict__ y_ws,
    const float* __restrict__ Wo, const float* __restrict__ bo,
    float* __restrict__ out)
{
    const int token = blockIdx.x;
    const int tid = threadIdx.x;
    __shared__ float sy[D_MODEL];
    sy[tid] = y_ws[token * D_MODEL + tid];
    __syncthreads();
    float acc = 0.f;
    #pragma unroll 8
    for (int i = 0; i < D_MODEL; ++i)
        acc += sy[i] * Wo[i * D_MODEL + tid];
    acc += bo[tid];
    out[token * D_MODEL + tid] = acc;
}

// ---------------------------------------------------------------------------
extern "C" void kernel_launch(void* const* d_in, const int* in_sizes, int n_in,
                              void* d_out, int out_size, void* d_ws, size_t ws_size,
                              hipStream_t stream)
{
    const float* x  = (const float*)d_in[0];
    const float* Wq = (const float*)d_in[1];
    const float* bq = (const float*)d_in[2];
    const float* Wk = (const float*)d_in[3];
    const float* bk = (const float*)d_in[4];
    const float* Wv = (const float*)d_in[5];
    const float* bv = (const float*)d_in[6];
    const float* Wo = (const float*)d_in[7];
    const float* bo = (const float*)d_in[8];
    const float* ls = (const float*)d_in[9];
    float* out = (float*)d_out;

    const int NTOK = BATCH * TLEN;                 // 4096
    char* ws = (char*)d_ws;
    size_t off = 0;
    float* q_ws    = (float*)(ws + off); off += (size_t)NTOK * D_STATE * 4;   // 1 MB
    float* k_ws    = (float*)(ws + off); off += (size_t)NTOK * D_STATE * 4;   // 1 MB
    float* v_ws    = (float*)(ws + off); off += (size_t)NTOK * D_MODEL * 4;   // 4 MB
    float* y_ws    = (float*)(ws + off); off += (size_t)NTOK * D_MODEL * 4;   // 4 MB
    float* sims_ws = (float*)(ws + off); off += (size_t)NTOK * MCON * 4;      // 1 MB
    int*   ver_ws  = (int*)  (ws + off); off += (size_t)NTOK * MCON * 4;      // 1 MB
    int*   n_ws    = (int*)  (ws + off); off += (size_t)NTOK * 4;             // 16 KB
    float* vlog_ws = (float*)(ws + off);                                      // 4.1 MB

    proj_kernel<<<NTOK, 256, 0, stream>>>(x, Wq, bq, Wk, bk, Wv, bv,
                                          q_ws, k_ws, v_ws);
    scan_kernel<<<BATCH, 256, 0, stream>>>(q_ws, k_ws, v_ws,
                                           sims_ws, n_ws, ver_ws, vlog_ws, ls);
    z_kernel<<<NTOK, 256, 0, stream>>>(sims_ws, n_ws, ver_ws, vlog_ws,
                                       y_ws, ls);
    out_kernel<<<NTOK, 256, 0, stream>>>(y_ws, Wo, bo, out);
}

// Round 14
// 1128.189 us; speedup vs baseline: 1.4241x; 1.0390x over previous
//
#include <hip/hip_runtime.h>
#include <hip/hip_bf16.h>

#define D_MODEL 256
#define D_STATE 64
#define MCON    64
#define TLEN    1024
#define BATCH   4
#define NEG_INF -1e9f
#define CSTRIDE 68

// LDS-ordered workgroup barrier (no vmcnt drain)
#define BAR() asm volatile("s_waitcnt lgkmcnt(0)\n\ts_barrier" ::: "memory")

// ---------------- DPP wave-64 helpers ----------------
template <int CTRL, int RM>
__device__ __forceinline__ float dpp_f(float x) {
    int xi = __float_as_int(x);
    int r  = __builtin_amdgcn_update_dpp(xi, xi, CTRL, RM, 0xf, false);
    return __int_as_float(r);
}
__device__ __forceinline__ float bcast_lane(float x, int lane) {
    return __int_as_float(__builtin_amdgcn_readlane(__float_as_int(x), lane));
}
__device__ __forceinline__ float wave_sum(float x) {
    x += dpp_f<0x111, 0xf>(x);
    x += dpp_f<0x112, 0xf>(x);
    x += dpp_f<0x114, 0xf>(x);
    x += dpp_f<0x118, 0xf>(x);
    x += dpp_f<0x142, 0xa>(x);
    x += dpp_f<0x143, 0xc>(x);
    return bcast_lane(x, 63);
}
__device__ __forceinline__ float wave_max(float x) {
    x = fmaxf(x, dpp_f<0x111, 0xf>(x));
    x = fmaxf(x, dpp_f<0x112, 0xf>(x));
    x = fmaxf(x, dpp_f<0x114, 0xf>(x));
    x = fmaxf(x, dpp_f<0x118, 0xf>(x));
    x = fmaxf(x, dpp_f<0x142, 0xa>(x));
    x = fmaxf(x, dpp_f<0x143, 0xc>(x));
    return bcast_lane(x, 63);
}
// exact argmax with first-index tiebreak: fmax chain + equality ballot + ffs.
// fmaxf returns an operand bit-exactly (no NaNs here), so lg==mx is exact and
// ffs picks the lowest index — identical selection to the R8-validated tracker.
__device__ __forceinline__ int wave_argmax_fast(float lg, float mx) {
    const unsigned long long m = __ballot(lg == mx);
    return (int)(__ffsll((long long)m) - 1);
}
// quad_perm [1,0,3,2] — swap adjacent lane pairs
__device__ __forceinline__ float dpp_swap1(float x) {
    int xi = __float_as_int(x);
    return __int_as_float(__builtin_amdgcn_update_dpp(xi, xi, 0xB1, 0xf, 0xf, false));
}

// ---------------------------------------------------------------------------
// Kernel 1: per-token projections (unchanged — passed R2..R13).
// ---------------------------------------------------------------------------
__global__ __launch_bounds__(256) void proj_kernel(
    const float* __restrict__ x,
    const float* __restrict__ Wq, const float* __restrict__ bq,
    const float* __restrict__ Wk, const float* __restrict__ bk,
    const float* __restrict__ Wv, const float* __restrict__ bv,
    float* __restrict__ q_ws, float* __restrict__ k_ws, float* __restrict__ v_ws)
{
    const int token = blockIdx.x;
    const int tid = threadIdx.x;
    __shared__ float sx[D_MODEL];
    sx[tid] = x[token * D_MODEL + tid];
    __syncthreads();

    float acc = 0.f;
    #pragma unroll 8
    for (int i = 0; i < D_MODEL; ++i)
        acc += sx[i] * Wv[i * D_MODEL + tid];
    acc += bv[tid];
    v_ws[token * D_MODEL + tid] = acc;

    if (tid < 128) {
        const int j = tid & 63;
        const float* W  = (tid < 64) ? Wq : Wk;
        const float* bb = (tid < 64) ? bq : bk;
        float a = 0.f;
        #pragma unroll 8
        for (int i = 0; i < D_MODEL; ++i)
            a += sx[i] * W[i * D_STATE + j];
        a += bb[j];
        float s2 = a * a;
        #pragma unroll
        for (int off = 1; off < 64; off <<= 1) s2 += __shfl_xor(s2, off, 64);
        float nrm = fmaxf(sqrtf(s2), 1e-12f);
        float o = a / nrm;
        if (tid < 64) q_ws[token * D_STATE + j] = o;
        else          k_ws[token * D_STATE + j] = o;
    }
}

// ---------------------------------------------------------------------------
// Kernel 2: CONTROL scan — 4 waves, 1 barrier/step (R13 structure + fast argmax)
// ---------------------------------------------------------------------------
__global__ __launch_bounds__(256) void scan_kernel(
    const float* __restrict__ q_ws, const float* __restrict__ k_ws,
    const float* __restrict__ v_ws,
    float* __restrict__ sims_ws, int* __restrict__ n_ws,
    int* __restrict__ ver_ws, float* __restrict__ vlog_ws,
    const float* __restrict__ ls_p)
{
    const int b   = blockIdx.x;
    const int tid = threadIdx.x;
    const int l   = tid & 63;
    const int wv  = tid >> 6;
    const float scale = fminf(expf(ls_p[0]), 100.f);

    __shared__ __align__(16) float sCT[MCON * CSTRIDE];  // centroids (bulk only)
    __shared__ __align__(16) float sV[MCON * D_MODEL];   // values (wave1 only)
    __shared__ __align__(16) float sQ[2][D_STATE];
    __shared__ __align__(16) float sK[2][D_STATE];
    __shared__ __align__(16) float sBuf[2][MCON];        // bulkdot (sims_{t+1})
    __shared__ __align__(16) float sS2[2][MCON];         // sum(tmp^2) per row
    __shared__ float sFA[2];                             // f_add = k_t . q_{t+1}
    __shared__ int   sFlagChg[2];
    __shared__ int   sFlagUpd[2];

    // ---- init ----
    const float4 zero4 = make_float4(0.f, 0.f, 0.f, 0.f);
    for (int i = tid; i < MCON * CSTRIDE; i += 256) sCT[i] = 0.f;
    #pragma unroll
    for (int i = 0; i < 16; ++i) ((float4*)sV)[i * 256 + tid] = zero4;
    if (tid < MCON) { sBuf[0][tid] = 0.f; sS2[0][tid] = 0.f; }
    if (tid == 0) { sFA[0] = 0.f; sFlagChg[0] = -1; sFlagUpd[0] = 0; }

    const float* qg = q_ws + b * TLEN * D_STATE;
    const float* kg = k_ws + b * TLEN * D_STATE;
    const float* vg = v_ws + b * TLEN * D_MODEL;
    float* vlog_b   = vlog_ws + (size_t)b * (TLEN + 1) * D_MODEL;

    if (tid < 64) {
        *(float4*)&vlog_b[4 * l] = zero4;   // vlog slot 0 = zeros
        sQ[1][l] = qg[D_STATE + l];         // q_1 (TLEN > 1)
        sK[0][l] = kg[l];                   // k_0
    }

    // ---- per-wave persistent state ----
    float qcur = 0.f, kcur = 0.f, qnx2 = 0.f, knx = 0.f;
    if (wv == 0) {
        kcur = kg[l];
        qcur = qg[D_STATE + l];
        knx  = kg[D_STATE + l];
        qnx2 = qg[2 * D_STATE + l];
    }
    float  cnt_l = 0.f;
    int    ver_l = 0, n = 0, chg_prev = -1, upd_prev = 0;
    float4 vvt = zero4;
    if (wv == 1) vvt = *(const float4*)&vg[4 * l];   // v_0
    const int brow = ((wv - 2) << 5) + (l >> 1);     // valid wv>=2
    const int bh   = l & 1;
    float4 tprev[8], kprev[8];
    float  s2prev = 0.f;
    #pragma unroll
    for (int c = 0; c < 8; ++c) { tprev[c] = zero4; kprev[c] = zero4; }

    __syncthreads();   // init visible

    for (int t = 0; t < TLEN; ++t) {
        const int token = b * TLEN + t;
        const int pc = t & 1, pn = 1 - pc;

        if (wv >= 2) {
            // ---- 1) write back last step's changed row (if owned) ----
            const int chg  = sFlagChg[pc];
            const int updf = sFlagUpd[pc];
            if (chg == brow) {
                const float rn = 1.f / fmaxf(sqrtf(s2prev), 1e-12f);
                float* dst = &sCT[brow * CSTRIDE + 32 * bh];
                #pragma unroll
                for (int c = 0; c < 8; ++c) {
                    float4 o;
                    o.x = updf ? tprev[c].x * rn : kprev[c].x;
                    o.y = updf ? tprev[c].y * rn : kprev[c].y;
                    o.z = updf ? tprev[c].z * rn : kprev[c].z;
                    o.w = updf ? tprev[c].w * rn : kprev[c].w;
                    *(float4*)(dst + 4 * c) = o;
                }
            }
            // ---- 2) bulk: dot, tmp, s2 (reads own rows post-write) ----
            const float* crow = &sCT[brow * CSTRIDE + 32 * bh];
            const float* qrow = &sQ[pn][32 * bh];
            const float* krow = &sK[pc][32 * bh];
            float pa = 0.f, pb = 0.f, sa = 0.f, sb = 0.f;
            #pragma unroll
            for (int c = 0; c < 8; ++c) {
                const float4 c4 = *(const float4*)(crow + 4 * c);
                const float4 q4 = *(const float4*)(qrow + 4 * c);
                const float4 k4 = *(const float4*)(krow + 4 * c);
                float4 t4;
                t4.x = 0.9f * c4.x + 0.1f * k4.x;
                t4.y = 0.9f * c4.y + 0.1f * k4.y;
                t4.z = 0.9f * c4.z + 0.1f * k4.z;
                t4.w = 0.9f * c4.w + 0.1f * k4.w;
                if (c < 4) {
                    pa += c4.x * q4.x; pa += c4.y * q4.y;
                    pa += c4.z * q4.z; pa += c4.w * q4.w;
                    sa += t4.x * t4.x; sa += t4.y * t4.y;
                    sa += t4.z * t4.z; sa += t4.w * t4.w;
                } else {
                    pb += c4.x * q4.x; pb += c4.y * q4.y;
                    pb += c4.z * q4.z; pb += c4.w * q4.w;
                    sb += t4.x * t4.x; sb += t4.y * t4.y;
                    sb += t4.z * t4.z; sb += t4.w * t4.w;
                }
                tprev[c] = t4; kprev[c] = k4;
            }
            const float sd = pa + pb;
            const float dot = sd + dpp_swap1(sd);
            const float ss = sa + sb;
            const float s2 = ss + dpp_swap1(ss);
            s2prev = s2;
            if (bh == 0) { sBuf[pn][brow] = dot; sS2[pn][brow] = s2; }
        }

        if (wv == 0) {
            sQ[pc][l] = qnx2;
            sK[pn][l] = knx;
            const float fa = wave_sum(kcur * qcur);  // k_t . q_{t+1}
            if (l == 0) sFA[pn] = fa;
            kcur = knx; qcur = qnx2;
            const int tk2 = (t + 2 < TLEN) ? t + 2 : TLEN - 1;
            const int tq3 = (t + 3 < TLEN) ? t + 3 : TLEN - 1;
            knx  = kg[tk2 * D_STATE + l];
            qnx2 = qg[tq3 * D_STATE + l];
        }

        if (wv == 1) {
            // ---- patched sims via linearity ----
            const int   ip   = (chg_prev < 0) ? 0 : chg_prev;
            const float bufv = sBuf[pc][l];
            const float s2v  = sS2[pc][ip];
            const float fa   = sFA[pc];
            const float bdc  = bcast_lane(bufv, ip);
            const float fupd = (0.9f * bdc + 0.1f * fa)
                               / fmaxf(sqrtf(s2v), 1e-12f);
            const float fsim = upd_prev ? fupd : fa;
            const float simv = (l == chg_prev) ? fsim : bufv;

            // logs (pre-update views)
            sims_ws[(size_t)token * MCON + l] = simv;
            ver_ws[(size_t)token * MCON + l]  = ver_l;
            if (l == 0) n_ws[token] = n;

            // ---- fast argmax (identical selection semantics) ----
            const float lg = ((l < n) ? simv : NEG_INF) * scale;
            const float mx = wave_max(lg);
            const int   sel    = wave_argmax_fast(lg, mx);
            const float selSim = bcast_lane(simv,  sel);
            const float cnt    = bcast_lane(cnt_l, sel);

            const float4 vs = *(const float4*)&sV[sel * D_MODEL + 4 * l];
            const float4 vt = vvt;
            float r = (vs.x - vt.x) * (vs.x - vt.x)
                    + (vs.y - vt.y) * (vs.y - vt.y)
                    + (vs.z - vt.z) * (vs.z - vt.z)
                    + (vs.w - vt.w) * (vs.w - vt.w);
            const float residual = sqrtf(wave_sum(r) * (1.f / 256.f));

            const bool has = n > 0;
            const bool refine = has && (n < MCON) &&
                                (selSim < 0.75f || residual > 1.0f);
            const bool do_add    = ((!has) || refine) && (n < MCON);
            const bool do_update = has && !refine;
            const int  chg = do_update ? sel : n;

            float4 nv;
            nv.x = (vs.x * cnt + vt.x) / (cnt + 1.f);
            nv.y = (vs.y * cnt + vt.y) / (cnt + 1.f);
            nv.z = (vs.z * cnt + vt.z) / (cnt + 1.f);
            nv.w = (vs.w * cnt + vt.w) / (cnt + 1.f);
            float4 valV;
            valV.x = do_update ? nv.x : vt.x;
            valV.y = do_update ? nv.y : vt.y;
            valV.z = do_update ? nv.z : vt.z;
            valV.w = do_update ? nv.w : vt.w;
            *(float4*)&sV[chg * D_MODEL + 4 * l] = valV;     // same-wave order
            *(float4*)&vlog_b[(size_t)(t + 1) * D_MODEL + 4 * l] = valV;

            if (l == 0) { sFlagChg[pn] = chg; sFlagUpd[pn] = do_update ? 1 : 0; }

            if (l == sel && do_update) cnt_l = cnt + 1.f;
            if (l == n   && do_add)    cnt_l = 1.f;
            if (l == chg) ver_l = t + 1;
            n += do_add ? 1 : 0;
            chg_prev = chg; upd_prev = do_update ? 1 : 0;

            const int tk = (t + 1 < TLEN) ? t + 1 : t;
            vvt = *(const float4*)&vg[tk * D_MODEL + 4 * l];
        }

        BAR();   // single per-step barrier
    }
}

// ---------------------------------------------------------------------------
// Kernel 3: fused PAYLOAD — softmax from logs, z via version gather (to LDS),
// then out = z @ Wo + bo. Bit-identical values to the R13 z+out pair.
// ---------------------------------------------------------------------------
__global__ __launch_bounds__(256) void zout_kernel(
    const float* __restrict__ sims_ws, const int* __restrict__ n_ws,
    const int* __restrict__ ver_ws, const float* __restrict__ vlog_ws,
    const float* __restrict__ Wo, const float* __restrict__ bo,
    float* __restrict__ out, const float* __restrict__ ls_p)
{
    const int token = blockIdx.x;
    const int b     = token >> 10;           // TLEN = 1024
    const int tid   = threadIdx.x;
    const int l     = tid & 63;
    const int wv    = tid >> 6;
    const float scale = fminf(expf(ls_p[0]), 100.f);

    __shared__ float sWt[MCON];
    __shared__ int   sVer[MCON];
    __shared__ int   sNtok;
    __shared__ float sy[D_MODEL];

    if (tid == 0) sNtok = n_ws[token];
    if (wv == 1) sVer[l] = ver_ws[(size_t)token * MCON + l];
    if (wv == 0) {
        const float simv = sims_ws[(size_t)token * MCON + l];
        const int nt = n_ws[token];
        const float lg = ((l < nt) ? simv : NEG_INF) * scale;
        const float mx = wave_max(lg);
        const float e  = expf(lg - mx);
        const float sm = wave_sum(e);
        sWt[l] = e / sm;                      // nt==0 -> NaN, guarded below
    }
    __syncthreads();

    const int nt = sNtok;
    float z = 0.f;
    if (nt > 0) {
        const float* base = vlog_ws + (size_t)b * (TLEN + 1) * D_MODEL;
        #pragma unroll 8
        for (int m = 0; m < MCON; ++m) {
            const float wm = sWt[m];          // 0 for m >= nt
            z += wm * base[(size_t)sVer[m] * D_MODEL + tid];
        }
    }
    sy[tid] = z;
    __syncthreads();

    float acc = 0.f;
    #pragma unroll 8
    for (int i = 0; i < D_MODEL; ++i)
        acc += sy[i] * Wo[i * D_MODEL + tid];
    acc += bo[tid];
    out[(size_t)token * D_MODEL + tid] = acc;
}

// ---------------------------------------------------------------------------
extern "C" void kernel_launch(void* const* d_in, const int* in_sizes, int n_in,
                              void* d_out, int out_size, void* d_ws, size_t ws_size,
                              hipStream_t stream)
{
    const float* x  = (const float*)d_in[0];
    const float* Wq = (const float*)d_in[1];
    const float* bq = (const float*)d_in[2];
    const float* Wk = (const float*)d_in[3];
    const float* bk = (const float*)d_in[4];
    const float* Wv = (const float*)d_in[5];
    const float* bv = (const float*)d_in[6];
    const float* Wo = (const float*)d_in[7];
    const float* bo = (const float*)d_in[8];
    const float* ls = (const float*)d_in[9];
    float* out = (float*)d_out;

    const int NTOK = BATCH * TLEN;                 // 4096
    char* ws = (char*)d_ws;
    size_t off = 0;
    float* q_ws    = (float*)(ws + off); off += (size_t)NTOK * D_STATE * 4;   // 1 MB
    float* k_ws    = (float*)(ws + off); off += (size_t)NTOK * D_STATE * 4;   // 1 MB
    float* v_ws    = (float*)(ws + off); off += (size_t)NTOK * D_MODEL * 4;   // 4 MB
    float* sims_ws = (float*)(ws + off); off += (size_t)NTOK * MCON * 4;      // 1 MB
    int*   ver_ws  = (int*)  (ws + off); off += (size_t)NTOK * MCON * 4;      // 1 MB
    int*   n_ws    = (int*)  (ws + off); off += (size_t)NTOK * 4;             // 16 KB
    float* vlog_ws = (float*)(ws + off);                                      // 4.1 MB

    proj_kernel<<<NTOK, 256, 0, stream>>>(x, Wq, bq, Wk, bk, Wv, bv,
                                          q_ws, k_ws, v_ws);
    scan_kernel<<<BATCH, 256, 0, stream>>>(q_ws, k_ws, v_ws,
                                           sims_ws, n_ws, ver_ws, vlog_ws, ls);
    zout_kernel<<<NTOK, 256, 0, stream>>>(sims_ws, n_ws, ver_ws, vlog_ws,
                                          Wo, bo, out, ls);
}

// Round 15
// 939.045 us; speedup vs baseline: 1.7109x; 1.2014x over previous
//
#include <hip/hip_runtime.h>
#include <hip/hip_bf16.h>

#define D_MODEL 256
#define D_STATE 64
#define MCON    64
#define TLEN    1024
#define BATCH   4
#define NEG_INF -1e9f

// LDS-ordered workgroup barrier (no vmcnt drain)
#define BAR() asm volatile("s_waitcnt lgkmcnt(0)\n\ts_barrier" ::: "memory")

// ---------------- DPP wave-64 helpers ----------------
template <int CTRL, int RM>
__device__ __forceinline__ float dpp_f(float x) {
    int xi = __float_as_int(x);
    int r  = __builtin_amdgcn_update_dpp(xi, xi, CTRL, RM, 0xf, false);
    return __int_as_float(r);
}
__device__ __forceinline__ float bcast_lane(float x, int lane) {
    return __int_as_float(__builtin_amdgcn_readlane(__float_as_int(x), lane));
}
__device__ __forceinline__ float wave_sum(float x) {
    x += dpp_f<0x111, 0xf>(x);
    x += dpp_f<0x112, 0xf>(x);
    x += dpp_f<0x114, 0xf>(x);
    x += dpp_f<0x118, 0xf>(x);
    x += dpp_f<0x142, 0xa>(x);
    x += dpp_f<0x143, 0xc>(x);
    return bcast_lane(x, 63);
}
__device__ __forceinline__ float wave_max(float x) {
    x = fmaxf(x, dpp_f<0x111, 0xf>(x));
    x = fmaxf(x, dpp_f<0x112, 0xf>(x));
    x = fmaxf(x, dpp_f<0x114, 0xf>(x));
    x = fmaxf(x, dpp_f<0x118, 0xf>(x));
    x = fmaxf(x, dpp_f<0x142, 0xa>(x));
    x = fmaxf(x, dpp_f<0x143, 0xc>(x));
    return bcast_lane(x, 63);
}
// exact argmax with first-index tiebreak: fmax chain + equality ballot + ffs
// (fmaxf returns an operand bit-exactly; no NaNs here) — validated R14.
__device__ __forceinline__ int wave_argmax_fast(float lg, float mx) {
    const unsigned long long m = __ballot(lg == mx);
    return (int)(__ffsll((long long)m) - 1);
}
// quad_perm [1,0,3,2] — swap adjacent lane pairs
__device__ __forceinline__ float dpp_swap1(float x) {
    int xi = __float_as_int(x);
    return __int_as_float(__builtin_amdgcn_update_dpp(xi, xi, 0xB1, 0xf, 0xf, false));
}

// ---------------------------------------------------------------------------
// Kernel 1: per-token projections (unchanged — passed R2..R14).
// ---------------------------------------------------------------------------
__global__ __launch_bounds__(256) void proj_kernel(
    const float* __restrict__ x,
    const float* __restrict__ Wq, const float* __restrict__ bq,
    const float* __restrict__ Wk, const float* __restrict__ bk,
    const float* __restrict__ Wv, const float* __restrict__ bv,
    float* __restrict__ q_ws, float* __restrict__ k_ws, float* __restrict__ v_ws)
{
    const int token = blockIdx.x;
    const int tid = threadIdx.x;
    __shared__ float sx[D_MODEL];
    sx[tid] = x[token * D_MODEL + tid];
    __syncthreads();

    float acc = 0.f;
    #pragma unroll 8
    for (int i = 0; i < D_MODEL; ++i)
        acc += sx[i] * Wv[i * D_MODEL + tid];
    acc += bv[tid];
    v_ws[token * D_MODEL + tid] = acc;

    if (tid < 128) {
        const int j = tid & 63;
        const float* W  = (tid < 64) ? Wq : Wk;
        const float* bb = (tid < 64) ? bq : bk;
        float a = 0.f;
        #pragma unroll 8
        for (int i = 0; i < D_MODEL; ++i)
            a += sx[i] * W[i * D_STATE + j];
        a += bb[j];
        float s2 = a * a;
        #pragma unroll
        for (int off = 1; off < 64; off <<= 1) s2 += __shfl_xor(s2, off, 64);
        float nrm = fmaxf(sqrtf(s2), 1e-12f);
        float o = a / nrm;
        if (tid < 64) q_ws[token * D_STATE + j] = o;
        else          k_ws[token * D_STATE + j] = o;
    }
}

// ---------------------------------------------------------------------------
// Kernel 2: CONTROL scan — 4 waves, 1 barrier/step.
//  waves 2,3 (bulk): C rows live in REGISTERS (Creg[8] float4/lane = half-row).
//    Per step: apply last step's change via cndmask, then dot/tmp/s2 from
//    registers + broadcast sQ/sK reads (2 distinct LDS addresses per wave —
//    conflict-free). No sCT in LDS at all (kills the 8-way-conflict DS burst).
//  wave 1 (control): patch sims via linearity, fast argmax, V[sel] read,
//    residual, flags, V/count/ver updates, publish flags.
//  wave 0: q/k staging + f_add.
// All values bit-identical to R13/R14 (same trees; C values identical).
// ---------------------------------------------------------------------------
__global__ __launch_bounds__(256) void scan_kernel(
    const float* __restrict__ q_ws, const float* __restrict__ k_ws,
    const float* __restrict__ v_ws,
    float* __restrict__ sims_ws, int* __restrict__ n_ws,
    int* __restrict__ ver_ws, float* __restrict__ vlog_ws,
    const float* __restrict__ ls_p)
{
    const int b   = blockIdx.x;
    const int tid = threadIdx.x;
    const int l   = tid & 63;
    const int wv  = tid >> 6;
    const float scale = fminf(expf(ls_p[0]), 100.f);

    __shared__ __align__(16) float sV[MCON * D_MODEL];   // values (wave1 only)
    __shared__ __align__(16) float sQ[2][D_STATE];
    __shared__ __align__(16) float sK[2][D_STATE];
    __shared__ __align__(16) float sBuf[2][MCON];        // bulkdot (sims_{t+1})
    __shared__ __align__(16) float sS2[2][MCON];         // sum(tmp^2) per row
    __shared__ float sFA[2];                             // f_add = k_t . q_{t+1}
    __shared__ int   sFlagChg[2];
    __shared__ int   sFlagUpd[2];

    // ---- init ----
    const float4 zero4 = make_float4(0.f, 0.f, 0.f, 0.f);
    #pragma unroll
    for (int i = 0; i < 16; ++i) ((float4*)sV)[i * 256 + tid] = zero4;
    if (tid < MCON) { sBuf[0][tid] = 0.f; sS2[0][tid] = 0.f; }
    if (tid == 0) { sFA[0] = 0.f; sFlagChg[0] = -1; sFlagUpd[0] = 0; }

    const float* qg = q_ws + b * TLEN * D_STATE;
    const float* kg = k_ws + b * TLEN * D_STATE;
    const float* vg = v_ws + b * TLEN * D_MODEL;
    float* vlog_b   = vlog_ws + (size_t)b * (TLEN + 1) * D_MODEL;

    if (tid < 64) {
        *(float4*)&vlog_b[4 * l] = zero4;   // vlog slot 0 = zeros
        sQ[1][l] = qg[D_STATE + l];         // q_1 (TLEN > 1)
        sK[0][l] = kg[l];                   // k_0
    }

    // ---- per-wave persistent state ----
    float qcur = 0.f, kcur = 0.f, qnx2 = 0.f, knx = 0.f;
    if (wv == 0) {
        kcur = kg[l];
        qcur = qg[D_STATE + l];
        knx  = kg[D_STATE + l];
        qnx2 = qg[2 * D_STATE + l];
    }
    float  cnt_l = 0.f;
    int    ver_l = 0, n = 0, chg_prev = -1, upd_prev = 0;
    float4 vvt = zero4;
    if (wv == 1) vvt = *(const float4*)&vg[4 * l];   // v_0
    const int brow = ((wv - 2) << 5) + (l >> 1);     // valid wv>=2
    const int bh   = l & 1;
    float4 Creg[8];                                  // C[brow][32bh..32bh+31]
    float4 tprev[8], kprev[8];
    float  s2prev = 0.f;
    #pragma unroll
    for (int c = 0; c < 8; ++c) { Creg[c] = zero4; tprev[c] = zero4; kprev[c] = zero4; }

    __syncthreads();   // init visible

    for (int t = 0; t < TLEN; ++t) {
        const int token = b * TLEN + t;
        const int pc = t & 1, pn = 1 - pc;

        if (wv >= 2) {
            // ---- 1) apply last step's changed row to Creg (if owned) ----
            const int  chg  = sFlagChg[pc];
            const bool updf = sFlagUpd[pc] != 0;
            if (chg == brow) {
                const float rn = 1.f / fmaxf(sqrtf(s2prev), 1e-12f);
                #pragma unroll
                for (int c = 0; c < 8; ++c) {
                    Creg[c].x = updf ? tprev[c].x * rn : kprev[c].x;
                    Creg[c].y = updf ? tprev[c].y * rn : kprev[c].y;
                    Creg[c].z = updf ? tprev[c].z * rn : kprev[c].z;
                    Creg[c].w = updf ? tprev[c].w * rn : kprev[c].w;
                }
            }
            // ---- 2) bulk: dot, tmp, s2 from registers + broadcast q/k ----
            const float* qrow = &sQ[pn][32 * bh];
            const float* krow = &sK[pc][32 * bh];
            float pa = 0.f, pb = 0.f, sa = 0.f, sb = 0.f;
            #pragma unroll
            for (int c = 0; c < 8; ++c) {
                const float4 c4 = Creg[c];
                const float4 q4 = *(const float4*)(qrow + 4 * c);
                const float4 k4 = *(const float4*)(krow + 4 * c);
                float4 t4;
                t4.x = 0.9f * c4.x + 0.1f * k4.x;
                t4.y = 0.9f * c4.y + 0.1f * k4.y;
                t4.z = 0.9f * c4.z + 0.1f * k4.z;
                t4.w = 0.9f * c4.w + 0.1f * k4.w;
                if (c < 4) {
                    pa += c4.x * q4.x; pa += c4.y * q4.y;
                    pa += c4.z * q4.z; pa += c4.w * q4.w;
                    sa += t4.x * t4.x; sa += t4.y * t4.y;
                    sa += t4.z * t4.z; sa += t4.w * t4.w;
                } else {
                    pb += c4.x * q4.x; pb += c4.y * q4.y;
                    pb += c4.z * q4.z; pb += c4.w * q4.w;
                    sb += t4.x * t4.x; sb += t4.y * t4.y;
                    sb += t4.z * t4.z; sb += t4.w * t4.w;
                }
                tprev[c] = t4; kprev[c] = k4;
            }
            const float sd  = pa + pb;
            const float dot = sd + dpp_swap1(sd);   // full row dot (both lanes)
            const float ss  = sa + sb;
            const float s2  = ss + dpp_swap1(ss);   // full row s2 (both lanes)
            s2prev = s2;
            if (bh == 0) { sBuf[pn][brow] = dot; sS2[pn][brow] = s2; }
        }

        if (wv == 0) {
            sQ[pc][l] = qnx2;
            sK[pn][l] = knx;
            const float fa = wave_sum(kcur * qcur);  // k_t . q_{t+1}
            if (l == 0) sFA[pn] = fa;
            kcur = knx; qcur = qnx2;
            const int tk2 = (t + 2 < TLEN) ? t + 2 : TLEN - 1;
            const int tq3 = (t + 3 < TLEN) ? t + 3 : TLEN - 1;
            knx  = kg[tk2 * D_STATE + l];
            qnx2 = qg[tq3 * D_STATE + l];
        }

        if (wv == 1) {
            // ---- patched sims via linearity ----
            const int   ip   = (chg_prev < 0) ? 0 : chg_prev;
            const float bufv = sBuf[pc][l];
            const float s2v  = sS2[pc][ip];
            const float fa   = sFA[pc];
            const float bdc  = bcast_lane(bufv, ip);
            const float fupd = (0.9f * bdc + 0.1f * fa)
                               / fmaxf(sqrtf(s2v), 1e-12f);
            const float fsim = upd_prev ? fupd : fa;
            const float simv = (l == chg_prev) ? fsim : bufv;

            // logs (pre-update views)
            sims_ws[(size_t)token * MCON + l] = simv;
            ver_ws[(size_t)token * MCON + l]  = ver_l;
            if (l == 0) n_ws[token] = n;

            // ---- fast argmax ----
            const float lg = ((l < n) ? simv : NEG_INF) * scale;
            const float mx = wave_max(lg);
            const int   sel    = wave_argmax_fast(lg, mx);
            const float selSim = bcast_lane(simv,  sel);
            const float cnt    = bcast_lane(cnt_l, sel);

            const float4 vs = *(const float4*)&sV[sel * D_MODEL + 4 * l];
            const float4 vt = vvt;
            float r = (vs.x - vt.x) * (vs.x - vt.x)
                    + (vs.y - vt.y) * (vs.y - vt.y)
                    + (vs.z - vt.z) * (vs.z - vt.z)
                    + (vs.w - vt.w) * (vs.w - vt.w);
            const float residual = sqrtf(wave_sum(r) * (1.f / 256.f));

            const bool has = n > 0;
            const bool refine = has && (n < MCON) &&
                                (selSim < 0.75f || residual > 1.0f);
            const bool do_add    = ((!has) || refine) && (n < MCON);
            const bool do_update = has && !refine;
            const int  chg = do_update ? sel : n;

            float4 nv;
            nv.x = (vs.x * cnt + vt.x) / (cnt + 1.f);
            nv.y = (vs.y * cnt + vt.y) / (cnt + 1.f);
            nv.z = (vs.z * cnt + vt.z) / (cnt + 1.f);
            nv.w = (vs.w * cnt + vt.w) / (cnt + 1.f);
            float4 valV;
            valV.x = do_update ? nv.x : vt.x;
            valV.y = do_update ? nv.y : vt.y;
            valV.z = do_update ? nv.z : vt.z;
            valV.w = do_update ? nv.w : vt.w;
            *(float4*)&sV[chg * D_MODEL + 4 * l] = valV;     // same-wave order
            *(float4*)&vlog_b[(size_t)(t + 1) * D_MODEL + 4 * l] = valV;

            if (l == 0) { sFlagChg[pn] = chg; sFlagUpd[pn] = do_update ? 1 : 0; }

            if (l == sel && do_update) cnt_l = cnt + 1.f;
            if (l == n   && do_add)    cnt_l = 1.f;
            if (l == chg) ver_l = t + 1;
            n += do_add ? 1 : 0;
            chg_prev = chg; upd_prev = do_update ? 1 : 0;

            const int tk = (t + 1 < TLEN) ? t + 1 : t;
            vvt = *(const float4*)&vg[tk * D_MODEL + 4 * l];
        }

        BAR();   // single per-step barrier
    }
}

// ---------------------------------------------------------------------------
// Kernel 3: fused PAYLOAD (unchanged — passed R14).
// ---------------------------------------------------------------------------
__global__ __launch_bounds__(256) void zout_kernel(
    const float* __restrict__ sims_ws, const int* __restrict__ n_ws,
    const int* __restrict__ ver_ws, const float* __restrict__ vlog_ws,
    const float* __restrict__ Wo, const float* __restrict__ bo,
    float* __restrict__ out, const float* __restrict__ ls_p)
{
    const int token = blockIdx.x;
    const int b     = token >> 10;           // TLEN = 1024
    const int tid   = threadIdx.x;
    const int l     = tid & 63;
    const int wv    = tid >> 6;
    const float scale = fminf(expf(ls_p[0]), 100.f);

    __shared__ float sWt[MCON];
    __shared__ int   sVer[MCON];
    __shared__ int   sNtok;
    __shared__ float sy[D_MODEL];

    if (tid == 0) sNtok = n_ws[token];
    if (wv == 1) sVer[l] = ver_ws[(size_t)token * MCON + l];
    if (wv == 0) {
        const float simv = sims_ws[(size_t)token * MCON + l];
        const int nt = n_ws[token];
        const float lg = ((l < nt) ? simv : NEG_INF) * scale;
        const float mx = wave_max(lg);
        const float e  = expf(lg - mx);
        const float sm = wave_sum(e);
        sWt[l] = e / sm;                      // nt==0 -> NaN, guarded below
    }
    __syncthreads();

    const int nt = sNtok;
    float z = 0.f;
    if (nt > 0) {
        const float* base = vlog_ws + (size_t)b * (TLEN + 1) * D_MODEL;
        #pragma unroll 8
        for (int m = 0; m < MCON; ++m) {
            const float wm = sWt[m];          // 0 for m >= nt
            z += wm * base[(size_t)sVer[m] * D_MODEL + tid];
        }
    }
    sy[tid] = z;
    __syncthreads();

    float acc = 0.f;
    #pragma unroll 8
    for (int i = 0; i < D_MODEL; ++i)
        acc += sy[i] * Wo[i * D_MODEL + tid];
    acc += bo[tid];
    out[(size_t)token * D_MODEL + tid] = acc;
}

// ---------------------------------------------------------------------------
extern "C" void kernel_launch(void* const* d_in, const int* in_sizes, int n_in,
                              void* d_out, int out_size, void* d_ws, size_t ws_size,
                              hipStream_t stream)
{
    const float* x  = (const float*)d_in[0];
    const float* Wq = (const float*)d_in[1];
    const float* bq = (const float*)d_in[2];
    const float* Wk = (const float*)d_in[3];
    const float* bk = (const float*)d_in[4];
    const float* Wv = (const float*)d_in[5];
    const float* bv = (const float*)d_in[6];
    const float* Wo = (const float*)d_in[7];
    const float* bo = (const float*)d_in[8];
    const float* ls = (const float*)d_in[9];
    float* out = (float*)d_out;

    const int NTOK = BATCH * TLEN;                 // 4096
    char* ws = (char*)d_ws;
    size_t off = 0;
    float* q_ws    = (float*)(ws + off); off += (size_t)NTOK * D_STATE * 4;   // 1 MB
    float* k_ws    = (float*)(ws + off); off += (size_t)NTOK * D_STATE * 4;   // 1 MB
    float* v_ws    = (float*)(ws + off); off += (size_t)NTOK * D_MODEL * 4;   // 4 MB
    float* sims_ws = (float*)(ws + off); off += (size_t)NTOK * MCON * 4;      // 1 MB
    int*   ver_ws  = (int*)  (ws + off); off += (size_t)NTOK * MCON * 4;      // 1 MB
    int*   n_ws    = (int*)  (ws + off); off += (size_t)NTOK * 4;             // 16 KB
    float* vlog_ws = (float*)(ws + off);                                      // 4.1 MB

    proj_kernel<<<NTOK, 256, 0, stream>>>(x, Wq, bq, Wk, bk, Wv, bv,
                                          q_ws, k_ws, v_ws);
    scan_kernel<<<BATCH, 256, 0, stream>>>(q_ws, k_ws, v_ws,
                                           sims_ws, n_ws, ver_ws, vlog_ws, ls);
    zout_kernel<<<NTOK, 256, 0, stream>>>(sims_ws, n_ws, ver_ws, vlog_ws,
                                          Wo, bo, out, ls);
}

// Round 16
// 926.061 us; speedup vs baseline: 1.7349x; 1.0140x over previous
//
#include <hip/hip_runtime.h>
#include <hip/hip_bf16.h>

#define D_MODEL 256
#define D_STATE 64
#define MCON    64
#define TLEN    1024
#define BATCH   4
#define NEG_INF -1e9f
#define PT      16     // tokens per proj block
#define ZT      8      // tokens per zout block

// LDS-ordered workgroup barrier (no vmcnt drain)
#define BAR() asm volatile("s_waitcnt lgkmcnt(0)\n\ts_barrier" ::: "memory")

// ---------------- DPP wave-64 helpers ----------------
template <int CTRL, int RM>
__device__ __forceinline__ float dpp_f(float x) {
    int xi = __float_as_int(x);
    int r  = __builtin_amdgcn_update_dpp(xi, xi, CTRL, RM, 0xf, false);
    return __int_as_float(r);
}
__device__ __forceinline__ float bcast_lane(float x, int lane) {
    return __int_as_float(__builtin_amdgcn_readlane(__float_as_int(x), lane));
}
__device__ __forceinline__ float wave_sum(float x) {
    x += dpp_f<0x111, 0xf>(x);
    x += dpp_f<0x112, 0xf>(x);
    x += dpp_f<0x114, 0xf>(x);
    x += dpp_f<0x118, 0xf>(x);
    x += dpp_f<0x142, 0xa>(x);
    x += dpp_f<0x143, 0xc>(x);
    return bcast_lane(x, 63);
}
__device__ __forceinline__ float wave_max(float x) {
    x = fmaxf(x, dpp_f<0x111, 0xf>(x));
    x = fmaxf(x, dpp_f<0x112, 0xf>(x));
    x = fmaxf(x, dpp_f<0x114, 0xf>(x));
    x = fmaxf(x, dpp_f<0x118, 0xf>(x));
    x = fmaxf(x, dpp_f<0x142, 0xa>(x));
    x = fmaxf(x, dpp_f<0x143, 0xc>(x));
    return bcast_lane(x, 63);
}
// exact argmax with first-index tiebreak (validated R14/R15)
__device__ __forceinline__ int wave_argmax_fast(float lg, float mx) {
    const unsigned long long m = __ballot(lg == mx);
    return (int)(__ffsll((long long)m) - 1);
}
// quad_perm [1,0,3,2]
__device__ __forceinline__ float dpp_swap1(float x) {
    int xi = __float_as_int(x);
    return __int_as_float(__builtin_amdgcn_update_dpp(xi, xi, 0xB1, 0xf, 0xf, false));
}

// ---------------------------------------------------------------------------
// Kernel 1: projections, token-tiled (PT tokens/block). Per-token operation
// sequence identical to R2..R15 (i ascending, same expression forms, same
// 64-lane shfl butterfly) -> bit-identical outputs; only W traffic /PT.
// ---------------------------------------------------------------------------
__global__ __launch_bounds__(256) void proj_kernel(
    const float* __restrict__ x,
    const float* __restrict__ Wq, const float* __restrict__ bq,
    const float* __restrict__ Wk, const float* __restrict__ bk,
    const float* __restrict__ Wv, const float* __restrict__ bv,
    float* __restrict__ q_ws, float* __restrict__ k_ws, float* __restrict__ v_ws)
{
    const int tok0 = blockIdx.x * PT;
    const int tid  = threadIdx.x;
    __shared__ float sx[PT][D_MODEL];   // 16 KB

    #pragma unroll
    for (int tt = 0; tt < PT; ++tt)
        sx[tt][tid] = x[(size_t)(tok0 + tt) * D_MODEL + tid];
    __syncthreads();

    // v = x @ Wv + bv  (thread tid owns output dim tid; PT tokens at once)
    {
        float acc[PT];
        #pragma unroll
        for (int tt = 0; tt < PT; ++tt) acc[tt] = 0.f;
        for (int i = 0; i < D_MODEL; ++i) {
            const float w = Wv[i * D_MODEL + tid];
            #pragma unroll
            for (int tt = 0; tt < PT; ++tt) acc[tt] += sx[tt][i] * w;
        }
        const float bvi = bv[tid];
        #pragma unroll
        for (int tt = 0; tt < PT; ++tt)
            v_ws[(size_t)(tok0 + tt) * D_MODEL + tid] = acc[tt] + bvi;
    }

    // q (wave 0) / k (wave 1), l2-normalized per token
    if (tid < 128) {
        const int j = tid & 63;
        const float* W  = (tid < 64) ? Wq : Wk;
        const float* bb = (tid < 64) ? bq : bk;
        float a[PT];
        #pragma unroll
        for (int tt = 0; tt < PT; ++tt) a[tt] = 0.f;
        for (int i = 0; i < D_MODEL; ++i) {
            const float w = W[i * D_STATE + j];
            #pragma unroll
            for (int tt = 0; tt < PT; ++tt) a[tt] += sx[tt][i] * w;
        }
        const float bbj = bb[j];
        #pragma unroll
        for (int tt = 0; tt < PT; ++tt) {
            const float av = a[tt] + bbj;
            float s2 = av * av;
            #pragma unroll
            for (int off = 1; off < 64; off <<= 1) s2 += __shfl_xor(s2, off, 64);
            const float nrm = fmaxf(sqrtf(s2), 1e-12f);
            const float o = av / nrm;
            if (tid < 64) q_ws[(size_t)(tok0 + tt) * D_STATE + j] = o;
            else          k_ws[(size_t)(tok0 + tt) * D_STATE + j] = o;
        }
    }
}

// ---------------------------------------------------------------------------
// Kernel 2: CONTROL scan — unchanged from R15 (passed, 769 µs, 0 conflicts).
// ---------------------------------------------------------------------------
__global__ __launch_bounds__(256) void scan_kernel(
    const float* __restrict__ q_ws, const float* __restrict__ k_ws,
    const float* __restrict__ v_ws,
    float* __restrict__ sims_ws, int* __restrict__ n_ws,
    int* __restrict__ ver_ws, float* __restrict__ vlog_ws,
    const float* __restrict__ ls_p)
{
    const int b   = blockIdx.x;
    const int tid = threadIdx.x;
    const int l   = tid & 63;
    const int wv  = tid >> 6;
    const float scale = fminf(expf(ls_p[0]), 100.f);

    __shared__ __align__(16) float sV[MCON * D_MODEL];   // values (wave1 only)
    __shared__ __align__(16) float sQ[2][D_STATE];
    __shared__ __align__(16) float sK[2][D_STATE];
    __shared__ __align__(16) float sBuf[2][MCON];        // bulkdot (sims_{t+1})
    __shared__ __align__(16) float sS2[2][MCON];         // sum(tmp^2) per row
    __shared__ float sFA[2];                             // f_add = k_t . q_{t+1}
    __shared__ int   sFlagChg[2];
    __shared__ int   sFlagUpd[2];

    const float4 zero4 = make_float4(0.f, 0.f, 0.f, 0.f);
    #pragma unroll
    for (int i = 0; i < 16; ++i) ((float4*)sV)[i * 256 + tid] = zero4;
    if (tid < MCON) { sBuf[0][tid] = 0.f; sS2[0][tid] = 0.f; }
    if (tid == 0) { sFA[0] = 0.f; sFlagChg[0] = -1; sFlagUpd[0] = 0; }

    const float* qg = q_ws + b * TLEN * D_STATE;
    const float* kg = k_ws + b * TLEN * D_STATE;
    const float* vg = v_ws + b * TLEN * D_MODEL;
    float* vlog_b   = vlog_ws + (size_t)b * (TLEN + 1) * D_MODEL;

    if (tid < 64) {
        *(float4*)&vlog_b[4 * l] = zero4;   // vlog slot 0 = zeros
        sQ[1][l] = qg[D_STATE + l];         // q_1
        sK[0][l] = kg[l];                   // k_0
    }

    float qcur = 0.f, kcur = 0.f, qnx2 = 0.f, knx = 0.f;
    if (wv == 0) {
        kcur = kg[l];
        qcur = qg[D_STATE + l];
        knx  = kg[D_STATE + l];
        qnx2 = qg[2 * D_STATE + l];
    }
    float  cnt_l = 0.f;
    int    ver_l = 0, n = 0, chg_prev = -1, upd_prev = 0;
    float4 vvt = zero4;
    if (wv == 1) vvt = *(const float4*)&vg[4 * l];   // v_0
    const int brow = ((wv - 2) << 5) + (l >> 1);
    const int bh   = l & 1;
    float4 Creg[8];
    float4 tprev[8], kprev[8];
    float  s2prev = 0.f;
    #pragma unroll
    for (int c = 0; c < 8; ++c) { Creg[c] = zero4; tprev[c] = zero4; kprev[c] = zero4; }

    __syncthreads();

    for (int t = 0; t < TLEN; ++t) {
        const int token = b * TLEN + t;
        const int pc = t & 1, pn = 1 - pc;

        if (wv >= 2) {
            const int  chg  = sFlagChg[pc];
            const bool updf = sFlagUpd[pc] != 0;
            if (chg == brow) {
                const float rn = 1.f / fmaxf(sqrtf(s2prev), 1e-12f);
                #pragma unroll
                for (int c = 0; c < 8; ++c) {
                    Creg[c].x = updf ? tprev[c].x * rn : kprev[c].x;
                    Creg[c].y = updf ? tprev[c].y * rn : kprev[c].y;
                    Creg[c].z = updf ? tprev[c].z * rn : kprev[c].z;
                    Creg[c].w = updf ? tprev[c].w * rn : kprev[c].w;
                }
            }
            const float* qrow = &sQ[pn][32 * bh];
            const float* krow = &sK[pc][32 * bh];
            float pa = 0.f, pb = 0.f, sa = 0.f, sb = 0.f;
            #pragma unroll
            for (int c = 0; c < 8; ++c) {
                const float4 c4 = Creg[c];
                const float4 q4 = *(const float4*)(qrow + 4 * c);
                const float4 k4 = *(const float4*)(krow + 4 * c);
                float4 t4;
                t4.x = 0.9f * c4.x + 0.1f * k4.x;
                t4.y = 0.9f * c4.y + 0.1f * k4.y;
                t4.z = 0.9f * c4.z + 0.1f * k4.z;
                t4.w = 0.9f * c4.w + 0.1f * k4.w;
                if (c < 4) {
                    pa += c4.x * q4.x; pa += c4.y * q4.y;
                    pa += c4.z * q4.z; pa += c4.w * q4.w;
                    sa += t4.x * t4.x; sa += t4.y * t4.y;
                    sa += t4.z * t4.z; sa += t4.w * t4.w;
                } else {
                    pb += c4.x * q4.x; pb += c4.y * q4.y;
                    pb += c4.z * q4.z; pb += c4.w * q4.w;
                    sb += t4.x * t4.x; sb += t4.y * t4.y;
                    sb += t4.z * t4.z; sb += t4.w * t4.w;
                }
                tprev[c] = t4; kprev[c] = k4;
            }
            const float sd  = pa + pb;
            const float dot = sd + dpp_swap1(sd);
            const float ss  = sa + sb;
            const float s2  = ss + dpp_swap1(ss);
            s2prev = s2;
            if (bh == 0) { sBuf[pn][brow] = dot; sS2[pn][brow] = s2; }
        }

        if (wv == 0) {
            sQ[pc][l] = qnx2;
            sK[pn][l] = knx;
            const float fa = wave_sum(kcur * qcur);
            if (l == 0) sFA[pn] = fa;
            kcur = knx; qcur = qnx2;
            const int tk2 = (t + 2 < TLEN) ? t + 2 : TLEN - 1;
            const int tq3 = (t + 3 < TLEN) ? t + 3 : TLEN - 1;
            knx  = kg[tk2 * D_STATE + l];
            qnx2 = qg[tq3 * D_STATE + l];
        }

        if (wv == 1) {
            const int   ip   = (chg_prev < 0) ? 0 : chg_prev;
            const float bufv = sBuf[pc][l];
            const float s2v  = sS2[pc][ip];
            const float fa   = sFA[pc];
            const float bdc  = bcast_lane(bufv, ip);
            const float fupd = (0.9f * bdc + 0.1f * fa)
                               / fmaxf(sqrtf(s2v), 1e-12f);
            const float fsim = upd_prev ? fupd : fa;
            const float simv = (l == chg_prev) ? fsim : bufv;

            sims_ws[(size_t)token * MCON + l] = simv;
            ver_ws[(size_t)token * MCON + l]  = ver_l;
            if (l == 0) n_ws[token] = n;

            const float lg = ((l < n) ? simv : NEG_INF) * scale;
            const float mx = wave_max(lg);
            const int   sel    = wave_argmax_fast(lg, mx);
            const float selSim = bcast_lane(simv,  sel);
            const float cnt    = bcast_lane(cnt_l, sel);

            const float4 vs = *(const float4*)&sV[sel * D_MODEL + 4 * l];
            const float4 vt = vvt;
            float r = (vs.x - vt.x) * (vs.x - vt.x)
                    + (vs.y - vt.y) * (vs.y - vt.y)
                    + (vs.z - vt.z) * (vs.z - vt.z)
                    + (vs.w - vt.w) * (vs.w - vt.w);
            const float residual = sqrtf(wave_sum(r) * (1.f / 256.f));

            const bool has = n > 0;
            const bool refine = has && (n < MCON) &&
                                (selSim < 0.75f || residual > 1.0f);
            const bool do_add    = ((!has) || refine) && (n < MCON);
            const bool do_update = has && !refine;
            const int  chg = do_update ? sel : n;

            float4 nv;
            nv.x = (vs.x * cnt + vt.x) / (cnt + 1.f);
            nv.y = (vs.y * cnt + vt.y) / (cnt + 1.f);
            nv.z = (vs.z * cnt + vt.z) / (cnt + 1.f);
            nv.w = (vs.w * cnt + vt.w) / (cnt + 1.f);
            float4 valV;
            valV.x = do_update ? nv.x : vt.x;
            valV.y = do_update ? nv.y : vt.y;
            valV.z = do_update ? nv.z : vt.z;
            valV.w = do_update ? nv.w : vt.w;
            *(float4*)&sV[chg * D_MODEL + 4 * l] = valV;
            *(float4*)&vlog_b[(size_t)(t + 1) * D_MODEL + 4 * l] = valV;

            if (l == 0) { sFlagChg[pn] = chg; sFlagUpd[pn] = do_update ? 1 : 0; }

            if (l == sel && do_update) cnt_l = cnt + 1.f;
            if (l == n   && do_add)    cnt_l = 1.f;
            if (l == chg) ver_l = t + 1;
            n += do_add ? 1 : 0;
            chg_prev = chg; upd_prev = do_update ? 1 : 0;

            const int tk = (t + 1 < TLEN) ? t + 1 : t;
            vvt = *(const float4*)&vg[tk * D_MODEL + 4 * l];
        }

        BAR();
    }
}

// ---------------------------------------------------------------------------
// Kernel 3: fused payload, token-tiled (ZT tokens/block). Per-token trees
// identical to R14/R15 -> bit-identical; Wo traffic /ZT.
// ---------------------------------------------------------------------------
__global__ __launch_bounds__(256) void zout_kernel(
    const float* __restrict__ sims_ws, const int* __restrict__ n_ws,
    const int* __restrict__ ver_ws, const float* __restrict__ vlog_ws,
    const float* __restrict__ Wo, const float* __restrict__ bo,
    float* __restrict__ out, const float* __restrict__ ls_p)
{
    const int tok0 = blockIdx.x * ZT;
    const int b    = tok0 >> 10;             // ZT divides TLEN -> same seq
    const int tid  = threadIdx.x;
    const int l    = tid & 63;
    const int wv   = tid >> 6;
    const float scale = fminf(expf(ls_p[0]), 100.f);

    __shared__ float sWt[ZT][MCON];
    __shared__ int   sVer[ZT][MCON];
    __shared__ int   sN[ZT];
    __shared__ float sy[ZT][D_MODEL];

    // softmax + ver loads: wave wv handles tokens tt = wv, wv+4, ...
    for (int tt = wv; tt < ZT; tt += 4) {
        const int token = tok0 + tt;
        const int nt = n_ws[token];
        if (l == 0) sN[tt] = nt;
        sVer[tt][l] = ver_ws[(size_t)token * MCON + l];
        const float simv = sims_ws[(size_t)token * MCON + l];
        const float lg = ((l < nt) ? simv : NEG_INF) * scale;
        const float mx = wave_max(lg);
        const float e  = expf(lg - mx);
        const float sm = wave_sum(e);
        sWt[tt][l] = e / sm;                 // nt==0 -> NaN, guarded below
    }
    __syncthreads();

    const float* base = vlog_ws + (size_t)b * (TLEN + 1) * D_MODEL;
    #pragma unroll
    for (int tt = 0; tt < ZT; ++tt) {
        float z = 0.f;
        if (sN[tt] > 0) {
            #pragma unroll 8
            for (int m = 0; m < MCON; ++m) {
                const float wm = sWt[tt][m];     // 0 for m >= nt
                z += wm * base[(size_t)sVer[tt][m] * D_MODEL + tid];
            }
        }
        sy[tt][tid] = z;
    }
    __syncthreads();

    float acc[ZT];
    #pragma unroll
    for (int tt = 0; tt < ZT; ++tt) acc[tt] = 0.f;
    for (int i = 0; i < D_MODEL; ++i) {
        const float wo = Wo[i * D_MODEL + tid];
        #pragma unroll
        for (int tt = 0; tt < ZT; ++tt) acc[tt] += sy[tt][i] * wo;
    }
    const float boi = bo[tid];
    #pragma unroll
    for (int tt = 0; tt < ZT; ++tt)
        out[(size_t)(tok0 + tt) * D_MODEL + tid] = acc[tt] + boi;
}

// ---------------------------------------------------------------------------
extern "C" void kernel_launch(void* const* d_in, const int* in_sizes, int n_in,
                              void* d_out, int out_size, void* d_ws, size_t ws_size,
                              hipStream_t stream)
{
    const float* x  = (const float*)d_in[0];
    const float* Wq = (const float*)d_in[1];
    const float* bq = (const float*)d_in[2];
    const float* Wk = (const float*)d_in[3];
    const float* bk = (const float*)d_in[4];
    const float* Wv = (const float*)d_in[5];
    const float* bv = (const float*)d_in[6];
    const float* Wo = (const float*)d_in[7];
    const float* bo = (const float*)d_in[8];
    const float* ls = (const float*)d_in[9];
    float* out = (float*)d_out;

    const int NTOK = BATCH * TLEN;                 // 4096
    char* ws = (char*)d_ws;
    size_t off = 0;
    float* q_ws    = (float*)(ws + off); off += (size_t)NTOK * D_STATE * 4;
    float* k_ws    = (float*)(ws + off); off += (size_t)NTOK * D_STATE * 4;
    float* v_ws    = (float*)(ws + off); off += (size_t)NTOK * D_MODEL * 4;
    float* sims_ws = (float*)(ws + off); off += (size_t)NTOK * MCON * 4;
    int*   ver_ws  = (int*)  (ws + off); off += (size_t)NTOK * MCON * 4;
    int*   n_ws    = (int*)  (ws + off); off += (size_t)NTOK * 4;
    float* vlog_ws = (float*)(ws + off);

    proj_kernel<<<NTOK / PT, 256, 0, stream>>>(x, Wq, bq, Wk, bk, Wv, bv,
                                               q_ws, k_ws, v_ws);
    scan_kernel<<<BATCH, 256, 0, stream>>>(q_ws, k_ws, v_ws,
                                           sims_ws, n_ws, ver_ws, vlog_ws, ls);
    zout_kernel<<<NTOK / ZT, 256, 0, stream>>>(sims_ws, n_ws, ver_ws, vlog_ws,
                                               Wo, bo, out, ls);
}